// Round 4
// baseline (289.882 us; speedup 1.0000x reference)
//
#include <hip/hip_runtime.h>
#include <stdint.h>

// B=4, T=1024, D=1024, H=16, DH=64. fp32 in/out, absmax thr 0.1.
// R4: flash computes S^T = K·Q^T so the post-softmax P fragment is ALREADY in
// the A-operand layout of a K=16 MFMA (C-layout row=quad*4+r==k matches
// A-layout k=quad*4+i). PV runs as mfma_f32_16x16x16_f16 on in-register P —
// no LDS, no transpose, no packing anywhere in flash. V is produced in fp16
// [B,H,DH,T] by the QKV GEMM epilogue.

#define B_  4
#define T_  1024
#define D_  1024
#define H_  16
#define DH_ 64

typedef __attribute__((ext_vector_type(8))) short short8;
typedef __attribute__((ext_vector_type(4))) float floatx4;
typedef __attribute__((ext_vector_type(4))) _Float16 half4;

__device__ __forceinline__ unsigned short f2bf(float f) {
  union { float f; uint32_t u; } a; a.f = f;
  uint32_t r = a.u + 0x7FFFu + ((a.u >> 16) & 1u);
  return (unsigned short)(r >> 16);
}
__device__ __forceinline__ float bf2f(unsigned short u) {
  union { uint32_t u; float f; } a; a.u = ((uint32_t)u) << 16;
  return a.f;
}

#define GLD_LDS16(g, l) __builtin_amdgcn_global_load_lds( \
    (const __attribute__((address_space(1))) unsigned int*)(g), \
    (__attribute__((address_space(3))) unsigned int*)(l), 16, 0, 0)

// ---------------------------------------------------------------- cast x
__global__ __launch_bounds__(256)
void cast_x_kernel(const float4* __restrict__ x4, unsigned short* __restrict__ xb) {
  int idx = blockIdx.x * 256 + threadIdx.x;
  float4 v = x4[idx];
  union { uint2 u; unsigned short s[4]; } o;
  o.s[0] = f2bf(v.x); o.s[1] = f2bf(v.y); o.s[2] = f2bf(v.z); o.s[3] = f2bf(v.w);
  *(uint2*)&xb[(size_t)idx * 4] = o.u;
}

// ------------------------------------------- transpose+cast weights -> B^T bf16
__global__ __launch_bounds__(256)
void transpose_cast_w(const float* __restrict__ w0, const float* __restrict__ w1,
                      const float* __restrict__ w2, const float* __restrict__ w3,
                      const float* __restrict__ w4, unsigned short* __restrict__ dst_all) {
  const int z = blockIdx.z;
  const float* src = (z == 0) ? w0 : (z == 1) ? w1 : (z == 2) ? w2 : (z == 3) ? w3 : w4;
  unsigned short* dst = dst_all + (size_t)z * D_ * D_;
  __shared__ __align__(16) unsigned short tile[64 * 72];
  const int t = threadIdx.x;
  const int k0 = blockIdx.y * 64, n0 = blockIdx.x * 64;
#pragma unroll
  for (int c = 0; c < 4; ++c) {
    int idx = c * 256 + t;
    int r = idx >> 4, cc = (idx & 15) << 2;
    float4 v = *(const float4*)&src[(size_t)(k0 + r) * D_ + n0 + cc];
    tile[(cc + 0) * 72 + r] = f2bf(v.x);
    tile[(cc + 1) * 72 + r] = f2bf(v.y);
    tile[(cc + 2) * 72 + r] = f2bf(v.z);
    tile[(cc + 3) * 72 + r] = f2bf(v.w);
  }
  __syncthreads();
  int rr = t >> 2, ck = (t & 3) << 4;
  uint4 v0 = *(const uint4*)&tile[rr * 72 + ck];
  uint4 v1 = *(const uint4*)&tile[rr * 72 + ck + 8];
  *(uint4*)&dst[(size_t)(n0 + rr) * D_ + k0 + ck] = v0;
  *(uint4*)&dst[(size_t)(n0 + rr) * D_ + k0 + ck + 8] = v1;
}

// ------------------------------------------------------------------ QKV GEMM
// 128x128 tile, BK=32, global_load_lds. Q,K bf16 -> [B,H,T,DH];
// V fp16 -> [B,H,DH,T] (transposed, for flash's PV B-operand).
__global__ __launch_bounds__(256, 2)
void gemm_qkv(const unsigned short* __restrict__ A,
              const unsigned short* __restrict__ Bt,
              unsigned short* __restrict__ oQ, unsigned short* __restrict__ oK,
              _Float16* __restrict__ oV) {
  const int K = 1024;
  __shared__ __align__(16) unsigned short As[128 * 32];
  __shared__ __align__(16) unsigned short Bs[128 * 32];
  const int t = threadIdx.x;
  const int lane = t & 63, w = t >> 6;
  const int quad = lane >> 4, lm = lane & 15;
  const int wm = w >> 1, wn = w & 1;
  const int m0 = blockIdx.y * 128, n0 = blockIdx.x * 128;
  const int arow = w * 32 + (lane >> 2), acol = (lane & 3) << 3;

  floatx4 acc[4][4];
#pragma unroll
  for (int i = 0; i < 4; ++i)
#pragma unroll
    for (int j = 0; j < 4; ++j) acc[i][j] = (floatx4){0.f, 0.f, 0.f, 0.f};

  for (int kt = 0; kt < K; kt += 32) {
    const unsigned short* ga = A + (size_t)(m0 + arow) * K + kt + acol;
    const unsigned short* gb = Bt + (size_t)(n0 + arow) * K + kt + acol;
    GLD_LDS16(ga, &As[(w * 32) * 32]);
    GLD_LDS16(ga + (size_t)16 * K, &As[(w * 32 + 16) * 32]);
    GLD_LDS16(gb, &Bs[(w * 32) * 32]);
    GLD_LDS16(gb + (size_t)16 * K, &Bs[(w * 32 + 16) * 32]);
    __syncthreads();
    short8 a[4], b[4];
#pragma unroll
    for (int i = 0; i < 4; ++i) a[i] = *(const short8*)&As[(wm * 64 + i * 16 + lm) * 32 + quad * 8];
#pragma unroll
    for (int j = 0; j < 4; ++j) b[j] = *(const short8*)&Bs[(wn * 64 + j * 16 + lm) * 32 + quad * 8];
#pragma unroll
    for (int i = 0; i < 4; ++i)
#pragma unroll
      for (int j = 0; j < 4; ++j)
        acc[i][j] = __builtin_amdgcn_mfma_f32_16x16x32_bf16(a[i], b[j], acc[i][j], 0, 0, 0);
    __syncthreads();
  }

#pragma unroll
  for (int i = 0; i < 4; ++i) {
    int gmb = m0 + wm * 64 + i * 16 + quad * 4;
#pragma unroll
    for (int j = 0; j < 4; ++j) {
      int gn = n0 + wn * 64 + j * 16 + lm;
      int which = gn >> 10, nn = gn & 1023, hh = nn >> 6, dd = nn & 63;
#pragma unroll
      for (int r = 0; r < 4; ++r) {
        int gm = gmb + r;
        int bb = gm >> 10, tt = gm & 1023;
        float v = acc[i][j][r];
        if (which == 2) {
          oV[(((size_t)bb * H_ + hh) * DH_ + dd) * T_ + tt] = (_Float16)v;
        } else {
          unsigned short* p = (which == 0) ? oQ : oK;
          p[(((size_t)bb * H_ + hh) * T_ + tt) * DH_ + dd] = f2bf(v);
        }
      }
    }
  }
}

// ------------------------------------------------------------ FFN GEMM 64x128
template <int MODE>
__global__ __launch_bounds__(256, 2)
void gemm_ffn(const unsigned short* __restrict__ A,
              const unsigned short* __restrict__ Bt,
              unsigned short* __restrict__ oBf, float* __restrict__ oF,
              const float* __restrict__ bias) {
  const int K = 1024, N = 1024;
  __shared__ __align__(16) unsigned short As[64 * 32];
  __shared__ __align__(16) unsigned short Bs[128 * 32];
  const int t = threadIdx.x;
  const int lane = t & 63, w = t >> 6;
  const int quad = lane >> 4, lm = lane & 15;
  const int wm = w >> 1, wn = w & 1;
  const int m0 = blockIdx.y * 64, n0 = blockIdx.x * 128;
  const int lrow = lane >> 2, lcol = (lane & 3) << 3;

  floatx4 acc[2][4];
#pragma unroll
  for (int i = 0; i < 2; ++i)
#pragma unroll
    for (int j = 0; j < 4; ++j) acc[i][j] = (floatx4){0.f, 0.f, 0.f, 0.f};

  for (int kt = 0; kt < K; kt += 32) {
    const unsigned short* ga = A + (size_t)(m0 + w * 16 + lrow) * K + kt + lcol;
    const unsigned short* gb = Bt + (size_t)(n0 + w * 32 + lrow) * K + kt + lcol;
    GLD_LDS16(ga, &As[(w * 16) * 32]);
    GLD_LDS16(gb, &Bs[(w * 32) * 32]);
    GLD_LDS16(gb + (size_t)16 * K, &Bs[(w * 32 + 16) * 32]);
    __syncthreads();
    short8 a[2], b[4];
#pragma unroll
    for (int i = 0; i < 2; ++i) a[i] = *(const short8*)&As[(wm * 32 + i * 16 + lm) * 32 + quad * 8];
#pragma unroll
    for (int j = 0; j < 4; ++j) b[j] = *(const short8*)&Bs[(wn * 64 + j * 16 + lm) * 32 + quad * 8];
#pragma unroll
    for (int i = 0; i < 2; ++i)
#pragma unroll
      for (int j = 0; j < 4; ++j)
        acc[i][j] = __builtin_amdgcn_mfma_f32_16x16x32_bf16(a[i], b[j], acc[i][j], 0, 0, 0);
    __syncthreads();
  }

#pragma unroll
  for (int i = 0; i < 2; ++i) {
    int gmb = m0 + wm * 32 + i * 16 + quad * 4;
#pragma unroll
    for (int j = 0; j < 4; ++j) {
      int gn = n0 + wn * 64 + j * 16 + lm;
      float bv = bias[gn];
#pragma unroll
      for (int r = 0; r < 4; ++r) {
        int gm = gmb + r;
        float v = acc[i][j][r] + bv;
        if (MODE == 1) {
          oBf[(size_t)gm * N + gn] = f2bf(fmaxf(v, 0.f));
        } else {
          oF[(size_t)gm * N + gn] = v;
        }
      }
    }
  }
}

// --------------------------------------------------------------- flash attn
// 512 blocks x 256 thr; each wave independent, NO LDS anywhere.
// S^T = K·Q^T via mfma_16x16x32_bf16 (A=K rows, B=Q rows): output lane=q,
// row=quad*4+r=k  ==> post-softmax P is natively the A-operand of
// mfma_16x16x16_f16 (m=lane=q, k=quad*4+i). PV: B = V^T fp16 (lane=d,
// k=quad*4+i contiguous in [DH][T] global). Fixed-max softmax; row 1023
// (all-masked) left NaN and overwritten by last_row_kernel.
__global__ __launch_bounds__(256, 4)
void flash_attn(const unsigned short* __restrict__ Qb,
                const unsigned short* __restrict__ Kb,
                const _Float16* __restrict__ Vtg,
                const float* __restrict__ maskp,
                unsigned short* __restrict__ attn) {
  const int t = threadIdx.x;
  const int lane = t & 63, w = t >> 6;
  const int quad = lane >> 4, lm = lane & 15;

  // balanced decode: CU block-pair gets (qb, 7-qb) -> 9 iters/pair
  const int bid = blockIdx.x;
  const int hi = bid >> 8, lo = bid & 255;
  const int qraw = lo & 7;
  const int qb = hi ? (7 - qraw) : qraw;
  const int hb = (lo >> 3) | (hi << 5);
  const int hh = hb & 15, bb = hb >> 4;
  const int q0 = qb << 7;

  const size_t headoff = ((size_t)bb * H_ + hh) * T_ * DH_;
  const unsigned short* Qh = Qb + headoff;
  const unsigned short* Kh = Kb + headoff;
  const _Float16* Vh = Vtg + headoff;   // [DH][T] fp16

  // Q as B-operand frags (lane = q): rows q0 + w*32 + qg*16 + lm
  short8 qf[2][2];
#pragma unroll
  for (int qg = 0; qg < 2; ++qg)
#pragma unroll
    for (int ks = 0; ks < 2; ++ks)
      qf[qg][ks] = *(const short8*)(Qh + (size_t)(q0 + w * 32 + qg * 16 + lm) * 64 + ks * 32 + quad * 8);

  float lsum[2] = {0.f, 0.f};
  floatx4 acc[2][4];
#pragma unroll
  for (int qg = 0; qg < 2; ++qg)
#pragma unroll
    for (int j2 = 0; j2 < 4; ++j2) acc[qg][j2] = (floatx4){0.f, 0.f, 0.f, 0.f};

  const int qglob0 = q0 + w * 32 + lm;   // q for qg=0; +16 for qg=1

  for (int kb = qb; kb < 8; ++kb) {
    const int k0 = kb * 128;
    const bool need_mask = (kb == qb);
    const unsigned short* Kblk = Kh + (size_t)k0 * 64;

#pragma unroll
    for (int j = 0; j < 8; ++j) {
      // K as A-operand frags (lane = k-row within 16-tile)
      short8 kf0 = *(const short8*)(Kblk + (size_t)(j * 16 + lm) * 64 + quad * 8);
      short8 kf1 = *(const short8*)(Kblk + (size_t)(j * 16 + lm) * 64 + 32 + quad * 8);
      floatx4 st[2];
#pragma unroll
      for (int qg = 0; qg < 2; ++qg) {
        floatx4 z = (floatx4){0.f, 0.f, 0.f, 0.f};
        z = __builtin_amdgcn_mfma_f32_16x16x32_bf16(kf0, qf[qg][0], z, 0, 0, 0);
        st[qg] = __builtin_amdgcn_mfma_f32_16x16x32_bf16(kf1, qf[qg][1], z, 0, 0, 0);
      }
      // softmax (fixed max): element (qg,r): k = k0+j*16+quad*4+r, q = qglob0+qg*16
      half4 pa[2];
#pragma unroll
      for (int qg = 0; qg < 2; ++qg) {
        const int qg_q = qglob0 + qg * 16;
#pragma unroll
        for (int r = 0; r < 4; ++r) {
          int kg = k0 + j * 16 + quad * 4 + r;
          float v = st[qg][r] * 0.125f;
          if (need_mask && kg <= qg_q) v -= 10000.f;
          float p = __expf(v);
          lsum[qg] += p;
          pa[qg][r] = (_Float16)p;
        }
      }
      // PV: B = V^T frags (lane = d, k = quad*4..+3 contiguous fp16)
#pragma unroll
      for (int j2 = 0; j2 < 4; ++j2) {
        half4 vb = *(const half4*)(Vh + (size_t)(j2 * 16 + lm) * T_ + k0 + j * 16 + quad * 4);
        acc[0][j2] = __builtin_amdgcn_mfma_f32_16x16x16f16(pa[0], vb, acc[0][j2], 0, 0, 0);
        acc[1][j2] = __builtin_amdgcn_mfma_f32_16x16x16f16(pa[1], vb, acc[1][j2], 0, 0, 0);
      }
    }
  }

  // epilogue: lsum lives per lane (q = qglob0 + qg*16); reduce over quads,
  // broadcast to C-layout rows, scale, store bf16.
#pragma unroll
  for (int qg = 0; qg < 2; ++qg) {
    float l = lsum[qg];
    l += __shfl_xor(l, 16);
    l += __shfl_xor(l, 32);
    float s = maskp[bb * T_ + qglob0 + qg * 16] / l;
#pragma unroll
    for (int r = 0; r < 4; ++r) {
      float bsc = __shfl(s, quad * 4 + r);   // value for q-row quad*4+r (lanes 0..15 hold them)
      int tq = q0 + w * 32 + qg * 16 + quad * 4 + r;
#pragma unroll
      for (int j2 = 0; j2 < 4; ++j2)
        attn[((size_t)(bb * T_ + tq)) * D_ + hh * 64 + j2 * 16 + lm] = f2bf(acc[qg][j2][r] * bsc);
    }
  }
}

// ------------------------------------------------- row 1023 exact softmax fix
__global__ __launch_bounds__(256)
void last_row_kernel(const unsigned short* __restrict__ Qb,
                     const unsigned short* __restrict__ Kb,
                     const _Float16* __restrict__ Vtg,
                     const float* __restrict__ maskp,
                     unsigned short* __restrict__ attn) {
  const int hh = blockIdx.x, bb = blockIdx.y;
  const size_t headoff = ((size_t)bb * H_ + hh) * T_ * DH_;
  const unsigned short* Qh = Qb + headoff;
  const unsigned short* Kh = Kb + headoff;
  const _Float16* Vh = Vtg + headoff;   // [DH][T]
  __shared__ float qrow[64];
  __shared__ float ps[1024];
  __shared__ float red[256];
  const int t = threadIdx.x;
  if (t < 64) qrow[t] = bf2f(Qh[(size_t)1023 * 64 + t]);
  __syncthreads();
  float lp = 0.f;
#pragma unroll
  for (int c = 0; c < 4; ++c) {
    int key = c * 256 + t;
    const unsigned short* kr = Kh + (size_t)key * 64;
    float dot = 0.f;
#pragma unroll
    for (int d8 = 0; d8 < 8; ++d8) {
      union { uint4 q; unsigned short s[8]; } kk;
      kk.q = *(const uint4*)&kr[d8 * 8];
#pragma unroll
      for (int u = 0; u < 8; ++u) dot += qrow[d8 * 8 + u] * bf2f(kk.s[u]);
    }
    float p = __expf(dot * 0.125f);
    ps[key] = p;
    lp += p;
  }
  red[t] = lp;
  __syncthreads();
  for (int s = 128; s > 0; s >>= 1) {
    if (t < s) red[t] += red[t + s];
    __syncthreads();
  }
  float ltot = red[0];
  __syncthreads();
  const int d = t & 63, part = t >> 6;
  const _Float16* vr = Vh + (size_t)d * T_ + part * 256;
  float acc = 0.f;
#pragma unroll
  for (int c = 0; c < 32; ++c) {
    union { uint4 q; _Float16 h[8]; } vv;
    vv.q = *(const uint4*)&vr[c * 8];
#pragma unroll
    for (int u = 0; u < 8; ++u) acc += ps[part * 256 + c * 8 + u] * (float)vv.h[u];
  }
  red[t] = acc;
  __syncthreads();
  if (t < 64) {
    float tot = red[t] + red[t + 64] + red[t + 128] + red[t + 192];
    attn[((size_t)(bb * T_ + 1023)) * D_ + hh * 64 + t] =
        f2bf(tot / ltot * maskp[bb * T_ + 1023]);
  }
}

// --------------------------------------------- LN(x + attn_bf16) -> h1 f32+bf16
__global__ __launch_bounds__(256)
void ln_res_kernel(const float* __restrict__ xa, const unsigned short* __restrict__ attn,
                   const float* __restrict__ sc, const float* __restrict__ bi,
                   float* __restrict__ h, unsigned short* __restrict__ hb) {
  const int row = blockIdx.x, t = threadIdx.x;
  const int lane = t & 63, wid = t >> 6;
  size_t base = (size_t)row * D_ + t * 4;
  float4 a = *(const float4*)&xa[base];
  union { uint2 u; unsigned short s[4]; } au;
  au.u = *(const uint2*)&attn[base];
  float v0 = a.x + bf2f(au.s[0]), v1 = a.y + bf2f(au.s[1]);
  float v2 = a.z + bf2f(au.s[2]), v3 = a.w + bf2f(au.s[3]);
  float s1 = v0 + v1 + v2 + v3;
  float s2 = v0 * v0 + v1 * v1 + v2 * v2 + v3 * v3;
#pragma unroll
  for (int off = 32; off; off >>= 1) { s1 += __shfl_down(s1, off); s2 += __shfl_down(s2, off); }
  __shared__ float r1[4], r2[4];
  if (lane == 0) { r1[wid] = s1; r2[wid] = s2; }
  __syncthreads();
  s1 = r1[0] + r1[1] + r1[2] + r1[3];
  s2 = r2[0] + r2[1] + r2[2] + r2[3];
  float mean = s1 * (1.f / 1024.f);
  float var = s2 * (1.f / 1024.f) - mean * mean;
  float rstd = rsqrtf(var + 1e-5f);
  float4 sv = *(const float4*)&sc[t * 4];
  float4 bv = *(const float4*)&bi[t * 4];
  float o0 = (v0 - mean) * rstd * sv.x + bv.x;
  float o1 = (v1 - mean) * rstd * sv.y + bv.y;
  float o2 = (v2 - mean) * rstd * sv.z + bv.z;
  float o3 = (v3 - mean) * rstd * sv.w + bv.w;
  float4 ov = {o0, o1, o2, o3};
  *(float4*)&h[base] = ov;
  union { uint2 u; unsigned short s[4]; } ob;
  ob.s[0] = f2bf(o0); ob.s[1] = f2bf(o1); ob.s[2] = f2bf(o2); ob.s[3] = f2bf(o3);
  *(uint2*)&hb[base] = ob.u;
}

// --------------------------------------- out = LN(LN(h1+ffn,ln2),ln3)
__global__ __launch_bounds__(256)
void ln_double_kernel(const float* __restrict__ h1, const float* __restrict__ ffn,
                      const float* __restrict__ s2c, const float* __restrict__ b2c,
                      const float* __restrict__ s3c, const float* __restrict__ b3c,
                      float* __restrict__ out) {
  const int row = blockIdx.x, t = threadIdx.x;
  const int lane = t & 63, wid = t >> 6;
  size_t base = (size_t)row * D_ + t * 4;
  float4 a = *(const float4*)&h1[base];
  float4 b = *(const float4*)&ffn[base];
  float v0 = a.x + b.x, v1 = a.y + b.y, v2 = a.z + b.z, v3 = a.w + b.w;
  float s1 = v0 + v1 + v2 + v3;
  float s2 = v0 * v0 + v1 * v1 + v2 * v2 + v3 * v3;
#pragma unroll
  for (int off = 32; off; off >>= 1) { s1 += __shfl_down(s1, off); s2 += __shfl_down(s2, off); }
  __shared__ float ra[4], rb[4], rc[4], rd[4];
  if (lane == 0) { ra[wid] = s1; rb[wid] = s2; }
  __syncthreads();
  s1 = ra[0] + ra[1] + ra[2] + ra[3];
  s2 = rb[0] + rb[1] + rb[2] + rb[3];
  float mean = s1 * (1.f / 1024.f);
  float var = s2 * (1.f / 1024.f) - mean * mean;
  float rstd = rsqrtf(var + 1e-5f);
  float4 sv = *(const float4*)&s2c[t * 4];
  float4 bv = *(const float4*)&b2c[t * 4];
  float o0 = (v0 - mean) * rstd * sv.x + bv.x;
  float o1 = (v1 - mean) * rstd * sv.y + bv.y;
  float o2 = (v2 - mean) * rstd * sv.z + bv.z;
  float o3 = (v3 - mean) * rstd * sv.w + bv.w;
  float u1 = o0 + o1 + o2 + o3;
  float u2 = o0 * o0 + o1 * o1 + o2 * o2 + o3 * o3;
#pragma unroll
  for (int off = 32; off; off >>= 1) { u1 += __shfl_down(u1, off); u2 += __shfl_down(u2, off); }
  if (lane == 0) { rc[wid] = u1; rd[wid] = u2; }
  __syncthreads();
  u1 = rc[0] + rc[1] + rc[2] + rc[3];
  u2 = rd[0] + rd[1] + rd[2] + rd[3];
  float mean2 = u1 * (1.f / 1024.f);
  float var2 = u2 * (1.f / 1024.f) - mean2 * mean2;
  float rstd2 = rsqrtf(var2 + 1e-5f);
  float4 s3v = *(const float4*)&s3c[t * 4];
  float4 b3v = *(const float4*)&b3c[t * 4];
  float4 fo;
  fo.x = (o0 - mean2) * rstd2 * s3v.x + b3v.x;
  fo.y = (o1 - mean2) * rstd2 * s3v.y + b3v.y;
  fo.z = (o2 - mean2) * rstd2 * s3v.z + b3v.z;
  fo.w = (o3 - mean2) * rstd2 * s3v.w + b3v.w;
  *(float4*)&out[base] = fo;
}

// ------------------------------------------------------------------ launch
extern "C" void kernel_launch(void* const* d_in, const int* in_sizes, int n_in,
                              void* d_out, int out_size, void* d_ws, size_t ws_size,
                              hipStream_t stream) {
  (void)in_sizes; (void)n_in; (void)out_size; (void)ws_size;
  const float* x   = (const float*)d_in[0];
  const float* msk = (const float*)d_in[1];
  const float* wq  = (const float*)d_in[2];
  const float* wk  = (const float*)d_in[3];
  const float* wv  = (const float*)d_in[4];
  const float* w1  = (const float*)d_in[5];
  const float* b1  = (const float*)d_in[6];
  const float* w2  = (const float*)d_in[7];
  const float* b2  = (const float*)d_in[8];
  const float* l1s = (const float*)d_in[9];
  const float* l1b = (const float*)d_in[10];
  const float* l2s = (const float*)d_in[11];
  const float* l2b = (const float*)d_in[12];
  const float* l3s = (const float*)d_in[13];
  const float* l3b = (const float*)d_in[14];
  float* outp = (float*)d_out;

  char* ws = (char*)d_ws;
  unsigned short* xb   = (unsigned short*)(ws);                       // 8 MB
  unsigned short* wt   = (unsigned short*)(ws + ((size_t)8  << 20));  // 10 MB
  unsigned short* Qb   = (unsigned short*)(ws + ((size_t)18 << 20));  // 8 MB [B,H,T,DH]
  unsigned short* Kb   = (unsigned short*)(ws + ((size_t)26 << 20));  // 8 MB
  _Float16*       Vtg  = (_Float16*)(ws + ((size_t)34 << 20));        // 8 MB [B,H,DH,T] fp16
  unsigned short* attn = (unsigned short*)(ws + ((size_t)42 << 20));  // 8 MB bf16 [B,T,D]
  float* h1            = (float*)(ws + ((size_t)50 << 20));           // 16 MB
  unsigned short* h1b  = (unsigned short*)(ws + ((size_t)18 << 20));  // reuse Qb
  unsigned short* gb   = (unsigned short*)(ws + ((size_t)26 << 20));  // reuse Kb
  float* ffn           = (float*)(ws + ((size_t)34 << 20));           // reuse Vtg+attn

  cast_x_kernel<<<4096, 256, 0, stream>>>((const float4*)x, xb);
  transpose_cast_w<<<dim3(16, 16, 5), 256, 0, stream>>>(wq, wk, wv, w1, w2, wt);
  gemm_qkv<<<dim3(24, 32), 256, 0, stream>>>(xb, wt, Qb, Kb, Vtg);
  flash_attn<<<512, 256, 0, stream>>>(Qb, Kb, Vtg, msk, attn);
  last_row_kernel<<<dim3(16, 4), 256, 0, stream>>>(Qb, Kb, Vtg, msk, attn);
  ln_res_kernel<<<4096, 256, 0, stream>>>(x, attn, l1s, l1b, h1, h1b);
  gemm_ffn<1><<<dim3(8, 64), 256, 0, stream>>>(h1b, wt + (size_t)3 * 1024 * 1024, gb, nullptr, b1);
  gemm_ffn<2><<<dim3(8, 64), 256, 0, stream>>>(gb, wt + (size_t)4 * 1024 * 1024, nullptr, ffn, b2);
  ln_double_kernel<<<4096, 256, 0, stream>>>(h1, ffn, l2s, l2b, l3s, l3b, outp);
}

// Round 5
// 276.017 us; speedup vs baseline: 1.0502x; 1.0502x over previous
//
#include <hip/hip_runtime.h>
#include <stdint.h>

// B=4, T=1024, D=1024, H=16, DH=64. fp32 in/out, absmax thr 0.1.
// R5: flash keeps R4's S^T=K·Q^T layout trick (P lands natively in the
// A-operand layout of mfma_f32_16x16x16_f16 -> zero-LDS PV) but fixes R4's
// latency serialization: all K/V fragments for a k-block are bulk-loaded
// into register arrays at iteration top (~32 overlapped loads), and V is
// stored k-shuffled ([d][kb][quad][j][r]) so each lane's per-block V data
// is 64B contiguous (4x uint4 instead of 8 scattered 8B loads).

#define B_  4
#define T_  1024
#define D_  1024
#define H_  16
#define DH_ 64

typedef __attribute__((ext_vector_type(8))) short short8;
typedef __attribute__((ext_vector_type(4))) float floatx4;
typedef __attribute__((ext_vector_type(4))) _Float16 half4;

__device__ __forceinline__ unsigned short f2bf(float f) {
  union { float f; uint32_t u; } a; a.f = f;
  uint32_t r = a.u + 0x7FFFu + ((a.u >> 16) & 1u);
  return (unsigned short)(r >> 16);
}
__device__ __forceinline__ float bf2f(unsigned short u) {
  union { uint32_t u; float f; } a; a.u = ((uint32_t)u) << 16;
  return a.f;
}

#define GLD_LDS16(g, l) __builtin_amdgcn_global_load_lds( \
    (const __attribute__((address_space(1))) unsigned int*)(g), \
    (__attribute__((address_space(3))) unsigned int*)(l), 16, 0, 0)

// ---------------------------------------------------------------- cast x
__global__ __launch_bounds__(256)
void cast_x_kernel(const float4* __restrict__ x4, unsigned short* __restrict__ xb) {
  int idx = blockIdx.x * 256 + threadIdx.x;
  float4 v = x4[idx];
  union { uint2 u; unsigned short s[4]; } o;
  o.s[0] = f2bf(v.x); o.s[1] = f2bf(v.y); o.s[2] = f2bf(v.z); o.s[3] = f2bf(v.w);
  *(uint2*)&xb[(size_t)idx * 4] = o.u;
}

// ------------------------------------------- transpose+cast weights -> B^T bf16
__global__ __launch_bounds__(256)
void transpose_cast_w(const float* __restrict__ w0, const float* __restrict__ w1,
                      const float* __restrict__ w2, const float* __restrict__ w3,
                      const float* __restrict__ w4, unsigned short* __restrict__ dst_all) {
  const int z = blockIdx.z;
  const float* src = (z == 0) ? w0 : (z == 1) ? w1 : (z == 2) ? w2 : (z == 3) ? w3 : w4;
  unsigned short* dst = dst_all + (size_t)z * D_ * D_;
  __shared__ __align__(16) unsigned short tile[64 * 72];
  const int t = threadIdx.x;
  const int k0 = blockIdx.y * 64, n0 = blockIdx.x * 64;
#pragma unroll
  for (int c = 0; c < 4; ++c) {
    int idx = c * 256 + t;
    int r = idx >> 4, cc = (idx & 15) << 2;
    float4 v = *(const float4*)&src[(size_t)(k0 + r) * D_ + n0 + cc];
    tile[(cc + 0) * 72 + r] = f2bf(v.x);
    tile[(cc + 1) * 72 + r] = f2bf(v.y);
    tile[(cc + 2) * 72 + r] = f2bf(v.z);
    tile[(cc + 3) * 72 + r] = f2bf(v.w);
  }
  __syncthreads();
  int rr = t >> 2, ck = (t & 3) << 4;
  uint4 v0 = *(const uint4*)&tile[rr * 72 + ck];
  uint4 v1 = *(const uint4*)&tile[rr * 72 + ck + 8];
  *(uint4*)&dst[(size_t)(n0 + rr) * D_ + k0 + ck] = v0;
  *(uint4*)&dst[(size_t)(n0 + rr) * D_ + k0 + ck + 8] = v1;
}

// ------------------------------------------------------------------ QKV GEMM
// 128x128 tile, BK=32, global_load_lds. Q,K bf16 -> [B,H,T,DH];
// V fp16 -> k-shuffled V^T: per head [d][kb][quad][j][r] (kb=k>>7, j=(k>>4)&7,
// quad=(k>>2)&3, r=k&3) so flash reads 64B contiguous per lane per k-block.
__global__ __launch_bounds__(256, 2)
void gemm_qkv(const unsigned short* __restrict__ A,
              const unsigned short* __restrict__ Bt,
              unsigned short* __restrict__ oQ, unsigned short* __restrict__ oK,
              _Float16* __restrict__ oV) {
  const int K = 1024;
  __shared__ __align__(16) unsigned short As[128 * 32];
  __shared__ __align__(16) unsigned short Bs[128 * 32];
  const int t = threadIdx.x;
  const int lane = t & 63, w = t >> 6;
  const int quad = lane >> 4, lm = lane & 15;
  const int wm = w >> 1, wn = w & 1;
  const int m0 = blockIdx.y * 128, n0 = blockIdx.x * 128;
  const int arow = w * 32 + (lane >> 2), acol = (lane & 3) << 3;

  floatx4 acc[4][4];
#pragma unroll
  for (int i = 0; i < 4; ++i)
#pragma unroll
    for (int j = 0; j < 4; ++j) acc[i][j] = (floatx4){0.f, 0.f, 0.f, 0.f};

  for (int kt = 0; kt < K; kt += 32) {
    const unsigned short* ga = A + (size_t)(m0 + arow) * K + kt + acol;
    const unsigned short* gb = Bt + (size_t)(n0 + arow) * K + kt + acol;
    GLD_LDS16(ga, &As[(w * 32) * 32]);
    GLD_LDS16(ga + (size_t)16 * K, &As[(w * 32 + 16) * 32]);
    GLD_LDS16(gb, &Bs[(w * 32) * 32]);
    GLD_LDS16(gb + (size_t)16 * K, &Bs[(w * 32 + 16) * 32]);
    __syncthreads();
    short8 a[4], b[4];
#pragma unroll
    for (int i = 0; i < 4; ++i) a[i] = *(const short8*)&As[(wm * 64 + i * 16 + lm) * 32 + quad * 8];
#pragma unroll
    for (int j = 0; j < 4; ++j) b[j] = *(const short8*)&Bs[(wn * 64 + j * 16 + lm) * 32 + quad * 8];
#pragma unroll
    for (int i = 0; i < 4; ++i)
#pragma unroll
      for (int j = 0; j < 4; ++j)
        acc[i][j] = __builtin_amdgcn_mfma_f32_16x16x32_bf16(a[i], b[j], acc[i][j], 0, 0, 0);
    __syncthreads();
  }

#pragma unroll
  for (int i = 0; i < 4; ++i) {
    int gmb = m0 + wm * 64 + i * 16 + quad * 4;
#pragma unroll
    for (int j = 0; j < 4; ++j) {
      int gn = n0 + wn * 64 + j * 16 + lm;
      int which = gn >> 10, nn = gn & 1023, hh = nn >> 6, dd = nn & 63;
#pragma unroll
      for (int r = 0; r < 4; ++r) {
        int gm = gmb + r;
        int bb = gm >> 10, tt = gm & 1023;
        float v = acc[i][j][r];
        if (which == 2) {
          // k-shuffled V^T store
          int kb = tt >> 7, jj = (tt >> 4) & 7, qd = (tt >> 2) & 3, rr2 = tt & 3;
          size_t off = ((((size_t)bb * H_ + hh) * DH_ + dd) * 8 + kb) * 128
                     + qd * 32 + jj * 4 + rr2;
          oV[off] = (_Float16)v;
        } else {
          unsigned short* p = (which == 0) ? oQ : oK;
          p[(((size_t)bb * H_ + hh) * T_ + tt) * DH_ + dd] = f2bf(v);
        }
      }
    }
  }
}

// ------------------------------------------------------------ FFN GEMM 64x128
template <int MODE>
__global__ __launch_bounds__(256, 2)
void gemm_ffn(const unsigned short* __restrict__ A,
              const unsigned short* __restrict__ Bt,
              unsigned short* __restrict__ oBf, float* __restrict__ oF,
              const float* __restrict__ bias) {
  const int K = 1024, N = 1024;
  __shared__ __align__(16) unsigned short As[64 * 32];
  __shared__ __align__(16) unsigned short Bs[128 * 32];
  const int t = threadIdx.x;
  const int lane = t & 63, w = t >> 6;
  const int quad = lane >> 4, lm = lane & 15;
  const int wm = w >> 1, wn = w & 1;
  const int m0 = blockIdx.y * 64, n0 = blockIdx.x * 128;
  const int lrow = lane >> 2, lcol = (lane & 3) << 3;

  floatx4 acc[2][4];
#pragma unroll
  for (int i = 0; i < 2; ++i)
#pragma unroll
    for (int j = 0; j < 4; ++j) acc[i][j] = (floatx4){0.f, 0.f, 0.f, 0.f};

  for (int kt = 0; kt < K; kt += 32) {
    const unsigned short* ga = A + (size_t)(m0 + w * 16 + lrow) * K + kt + lcol;
    const unsigned short* gb = Bt + (size_t)(n0 + w * 32 + lrow) * K + kt + lcol;
    GLD_LDS16(ga, &As[(w * 16) * 32]);
    GLD_LDS16(gb, &Bs[(w * 32) * 32]);
    GLD_LDS16(gb + (size_t)16 * K, &Bs[(w * 32 + 16) * 32]);
    __syncthreads();
    short8 a[2], b[4];
#pragma unroll
    for (int i = 0; i < 2; ++i) a[i] = *(const short8*)&As[(wm * 32 + i * 16 + lm) * 32 + quad * 8];
#pragma unroll
    for (int j = 0; j < 4; ++j) b[j] = *(const short8*)&Bs[(wn * 64 + j * 16 + lm) * 32 + quad * 8];
#pragma unroll
    for (int i = 0; i < 2; ++i)
#pragma unroll
      for (int j = 0; j < 4; ++j)
        acc[i][j] = __builtin_amdgcn_mfma_f32_16x16x32_bf16(a[i], b[j], acc[i][j], 0, 0, 0);
    __syncthreads();
  }

#pragma unroll
  for (int i = 0; i < 2; ++i) {
    int gmb = m0 + wm * 32 + i * 16 + quad * 4;
#pragma unroll
    for (int j = 0; j < 4; ++j) {
      int gn = n0 + wn * 64 + j * 16 + lm;
      float bv = bias[gn];
#pragma unroll
      for (int r = 0; r < 4; ++r) {
        int gm = gmb + r;
        float v = acc[i][j][r] + bv;
        if (MODE == 1) {
          oBf[(size_t)gm * N + gn] = f2bf(fmaxf(v, 0.f));
        } else {
          oF[(size_t)gm * N + gn] = v;
        }
      }
    }
  }
}

// --------------------------------------------------------------- flash attn
// 512 blocks x 256 thr; each wave independent, NO LDS. Per k-block all K/V
// fragments bulk-loaded into registers (overlapped latency), then 8 j-steps
// of S^T-mfma -> softmax -> in-register PV (mfma_16x16x16_f16).
__global__ __launch_bounds__(256, 2)
void flash_attn(const unsigned short* __restrict__ Qb,
                const unsigned short* __restrict__ Kb,
                const _Float16* __restrict__ Vtg,
                const float* __restrict__ maskp,
                unsigned short* __restrict__ attn) {
  const int t = threadIdx.x;
  const int lane = t & 63, w = t >> 6;
  const int quad = lane >> 4, lm = lane & 15;

  // balanced decode: CU block-pair gets (qb, 7-qb) -> 9 iters/pair
  const int bid = blockIdx.x;
  const int hi = bid >> 8, lo = bid & 255;
  const int qraw = lo & 7;
  const int qb = hi ? (7 - qraw) : qraw;
  const int hb = (lo >> 3) | (hi << 5);
  const int hh = hb & 15, bb = hb >> 4;
  const int q0 = qb << 7;

  const size_t headoff = ((size_t)bb * H_ + hh) * T_ * DH_;
  const unsigned short* Qh = Qb + headoff;
  const unsigned short* Kh = Kb + headoff;
  const _Float16* Vh = Vtg + headoff;   // k-shuffled [d][kb][quad][j][r]

  short8 qf[2][2];
#pragma unroll
  for (int qg = 0; qg < 2; ++qg)
#pragma unroll
    for (int ks = 0; ks < 2; ++ks)
      qf[qg][ks] = *(const short8*)(Qh + (size_t)(q0 + w * 32 + qg * 16 + lm) * 64 + ks * 32 + quad * 8);

  float lsum[2] = {0.f, 0.f};
  floatx4 acc[2][4];
#pragma unroll
  for (int qg = 0; qg < 2; ++qg)
#pragma unroll
    for (int j2 = 0; j2 < 4; ++j2) acc[qg][j2] = (floatx4){0.f, 0.f, 0.f, 0.f};

  const int qglob0 = q0 + w * 32 + lm;

  for (int kb = qb; kb < 8; ++kb) {
    const int k0 = kb * 128;
    const bool need_mask = (kb == qb);
    const unsigned short* Kblk = Kh + (size_t)k0 * 64;

    // ---- bulk loads: 16 K-frag short8 + 16 V uint4 (all independent) ----
    short8 kf[8][2];
#pragma unroll
    for (int j = 0; j < 8; ++j) {
      kf[j][0] = *(const short8*)(Kblk + (size_t)(j * 16 + lm) * 64 + quad * 8);
      kf[j][1] = *(const short8*)(Kblk + (size_t)(j * 16 + lm) * 64 + 32 + quad * 8);
    }
    union { uint4 u[4]; _Float16 h[32]; } vf[4];
#pragma unroll
    for (int j2 = 0; j2 < 4; ++j2) {
      const _Float16* vp = Vh + ((size_t)(j2 * 16 + lm) * 8 + kb) * 128 + quad * 32;
#pragma unroll
      for (int g = 0; g < 4; ++g) vf[j2].u[g] = *(const uint4*)(vp + g * 8);
    }

    // ---- compute ----
#pragma unroll
    for (int j = 0; j < 8; ++j) {
      floatx4 st[2];
#pragma unroll
      for (int qg = 0; qg < 2; ++qg) {
        floatx4 z = (floatx4){0.f, 0.f, 0.f, 0.f};
        z = __builtin_amdgcn_mfma_f32_16x16x32_bf16(kf[j][0], qf[qg][0], z, 0, 0, 0);
        st[qg] = __builtin_amdgcn_mfma_f32_16x16x32_bf16(kf[j][1], qf[qg][1], z, 0, 0, 0);
      }
      half4 pa[2];
#pragma unroll
      for (int qg = 0; qg < 2; ++qg) {
        const int qg_q = qglob0 + qg * 16;
#pragma unroll
        for (int r = 0; r < 4; ++r) {
          int kg = k0 + j * 16 + quad * 4 + r;
          float v = st[qg][r] * 0.125f;
          if (need_mask && kg <= qg_q) v -= 10000.f;
          float p = __expf(v);
          lsum[qg] += p;
          pa[qg][r] = (_Float16)p;
        }
      }
#pragma unroll
      for (int j2 = 0; j2 < 4; ++j2) {
        half4 vb;
#pragma unroll
        for (int r = 0; r < 4; ++r) vb[r] = vf[j2].h[j * 4 + r];
        acc[0][j2] = __builtin_amdgcn_mfma_f32_16x16x16f16(pa[0], vb, acc[0][j2], 0, 0, 0);
        acc[1][j2] = __builtin_amdgcn_mfma_f32_16x16x16f16(pa[1], vb, acc[1][j2], 0, 0, 0);
      }
    }
  }

  // epilogue
#pragma unroll
  for (int qg = 0; qg < 2; ++qg) {
    float l = lsum[qg];
    l += __shfl_xor(l, 16);
    l += __shfl_xor(l, 32);
    float s = maskp[bb * T_ + qglob0 + qg * 16] / l;
#pragma unroll
    for (int r = 0; r < 4; ++r) {
      float bsc = __shfl(s, quad * 4 + r);
      int tq = q0 + w * 32 + qg * 16 + quad * 4 + r;
#pragma unroll
      for (int j2 = 0; j2 < 4; ++j2)
        attn[((size_t)(bb * T_ + tq)) * D_ + hh * 64 + j2 * 16 + lm] = f2bf(acc[qg][j2][r] * bsc);
    }
  }
}

// ------------------------------------------------- row 1023 exact softmax fix
__global__ __launch_bounds__(256)
void last_row_kernel(const unsigned short* __restrict__ Qb,
                     const unsigned short* __restrict__ Kb,
                     const _Float16* __restrict__ Vtg,
                     const float* __restrict__ maskp,
                     unsigned short* __restrict__ attn) {
  const int hh = blockIdx.x, bb = blockIdx.y;
  const size_t headoff = ((size_t)bb * H_ + hh) * T_ * DH_;
  const unsigned short* Qh = Qb + headoff;
  const unsigned short* Kh = Kb + headoff;
  const _Float16* Vh = Vtg + headoff;   // k-shuffled
  __shared__ float qrow[64];
  __shared__ float ps[1024];
  __shared__ float red[256];
  const int t = threadIdx.x;
  if (t < 64) qrow[t] = bf2f(Qh[(size_t)1023 * 64 + t]);
  __syncthreads();
  float lp = 0.f;
#pragma unroll
  for (int c = 0; c < 4; ++c) {
    int key = c * 256 + t;
    const unsigned short* kr = Kh + (size_t)key * 64;
    float dot = 0.f;
#pragma unroll
    for (int d8 = 0; d8 < 8; ++d8) {
      union { uint4 q; unsigned short s[8]; } kk;
      kk.q = *(const uint4*)&kr[d8 * 8];
#pragma unroll
      for (int u = 0; u < 8; ++u) dot += qrow[d8 * 8 + u] * bf2f(kk.s[u]);
    }
    float p = __expf(dot * 0.125f);
    ps[key] = p;
    lp += p;
  }
  red[t] = lp;
  __syncthreads();
  for (int s = 128; s > 0; s >>= 1) {
    if (t < s) red[t] += red[t + s];
    __syncthreads();
  }
  float ltot = red[0];
  __syncthreads();
  const int d = t & 63, part = t >> 6;
  const _Float16* vr = Vh + (size_t)d * 1024 + part * 256;
  float acc = 0.f;
#pragma unroll
  for (int c = 0; c < 32; ++c) {
    union { uint4 q; _Float16 h[8]; } vv;
    vv.q = *(const uint4*)&vr[c * 8];
#pragma unroll
    for (int u = 0; u < 8; ++u) {
      int si = part * 256 + c * 8 + u;       // storage index
      int jj = (si >> 2) & 7, qd = (si >> 5) & 3, rr2 = si & 3;
      int kk = (si & ~127) + jj * 16 + qd * 4 + rr2;
      acc += ps[kk] * (float)vv.h[u];
    }
  }
  red[t] = acc;
  __syncthreads();
  if (t < 64) {
    float tot = red[t] + red[t + 64] + red[t + 128] + red[t + 192];
    attn[((size_t)(bb * T_ + 1023)) * D_ + hh * 64 + t] =
        f2bf(tot / ltot * maskp[bb * T_ + 1023]);
  }
}

// --------------------------------------------- LN(x + attn_bf16) -> h1 f32+bf16
__global__ __launch_bounds__(256)
void ln_res_kernel(const float* __restrict__ xa, const unsigned short* __restrict__ attn,
                   const float* __restrict__ sc, const float* __restrict__ bi,
                   float* __restrict__ h, unsigned short* __restrict__ hb) {
  const int row = blockIdx.x, t = threadIdx.x;
  const int lane = t & 63, wid = t >> 6;
  size_t base = (size_t)row * D_ + t * 4;
  float4 a = *(const float4*)&xa[base];
  union { uint2 u; unsigned short s[4]; } au;
  au.u = *(const uint2*)&attn[base];
  float v0 = a.x + bf2f(au.s[0]), v1 = a.y + bf2f(au.s[1]);
  float v2 = a.z + bf2f(au.s[2]), v3 = a.w + bf2f(au.s[3]);
  float s1 = v0 + v1 + v2 + v3;
  float s2 = v0 * v0 + v1 * v1 + v2 * v2 + v3 * v3;
#pragma unroll
  for (int off = 32; off; off >>= 1) { s1 += __shfl_down(s1, off); s2 += __shfl_down(s2, off); }
  __shared__ float r1[4], r2[4];
  if (lane == 0) { r1[wid] = s1; r2[wid] = s2; }
  __syncthreads();
  s1 = r1[0] + r1[1] + r1[2] + r1[3];
  s2 = r2[0] + r2[1] + r2[2] + r2[3];
  float mean = s1 * (1.f / 1024.f);
  float var = s2 * (1.f / 1024.f) - mean * mean;
  float rstd = rsqrtf(var + 1e-5f);
  float4 sv = *(const float4*)&sc[t * 4];
  float4 bv = *(const float4*)&bi[t * 4];
  float o0 = (v0 - mean) * rstd * sv.x + bv.x;
  float o1 = (v1 - mean) * rstd * sv.y + bv.y;
  float o2 = (v2 - mean) * rstd * sv.z + bv.z;
  float o3 = (v3 - mean) * rstd * sv.w + bv.w;
  float4 ov = {o0, o1, o2, o3};
  *(float4*)&h[base] = ov;
  union { uint2 u; unsigned short s[4]; } ob;
  ob.s[0] = f2bf(o0); ob.s[1] = f2bf(o1); ob.s[2] = f2bf(o2); ob.s[3] = f2bf(o3);
  *(uint2*)&hb[base] = ob.u;
}

// --------------------------------------- out = LN(LN(h1+ffn,ln2),ln3)
__global__ __launch_bounds__(256)
void ln_double_kernel(const float* __restrict__ h1, const float* __restrict__ ffn,
                      const float* __restrict__ s2c, const float* __restrict__ b2c,
                      const float* __restrict__ s3c, const float* __restrict__ b3c,
                      float* __restrict__ out) {
  const int row = blockIdx.x, t = threadIdx.x;
  const int lane = t & 63, wid = t >> 6;
  size_t base = (size_t)row * D_ + t * 4;
  float4 a = *(const float4*)&h1[base];
  float4 b = *(const float4*)&ffn[base];
  float v0 = a.x + b.x, v1 = a.y + b.y, v2 = a.z + b.z, v3 = a.w + b.w;
  float s1 = v0 + v1 + v2 + v3;
  float s2 = v0 * v0 + v1 * v1 + v2 * v2 + v3 * v3;
#pragma unroll
  for (int off = 32; off; off >>= 1) { s1 += __shfl_down(s1, off); s2 += __shfl_down(s2, off); }
  __shared__ float ra[4], rb[4], rc[4], rd[4];
  if (lane == 0) { ra[wid] = s1; rb[wid] = s2; }
  __syncthreads();
  s1 = ra[0] + ra[1] + ra[2] + ra[3];
  s2 = rb[0] + rb[1] + rb[2] + rb[3];
  float mean = s1 * (1.f / 1024.f);
  float var = s2 * (1.f / 1024.f) - mean * mean;
  float rstd = rsqrtf(var + 1e-5f);
  float4 sv = *(const float4*)&s2c[t * 4];
  float4 bv = *(const float4*)&b2c[t * 4];
  float o0 = (v0 - mean) * rstd * sv.x + bv.x;
  float o1 = (v1 - mean) * rstd * sv.y + bv.y;
  float o2 = (v2 - mean) * rstd * sv.z + bv.z;
  float o3 = (v3 - mean) * rstd * sv.w + bv.w;
  float u1 = o0 + o1 + o2 + o3;
  float u2 = o0 * o0 + o1 * o1 + o2 * o2 + o3 * o3;
#pragma unroll
  for (int off = 32; off; off >>= 1) { u1 += __shfl_down(u1, off); u2 += __shfl_down(u2, off); }
  if (lane == 0) { rc[wid] = u1; rd[wid] = u2; }
  __syncthreads();
  u1 = rc[0] + rc[1] + rc[2] + rc[3];
  u2 = rd[0] + rd[1] + rd[2] + rd[3];
  float mean2 = u1 * (1.f / 1024.f);
  float var2 = u2 * (1.f / 1024.f) - mean2 * mean2;
  float rstd2 = rsqrtf(var2 + 1e-5f);
  float4 s3v = *(const float4*)&s3c[t * 4];
  float4 b3v = *(const float4*)&b3c[t * 4];
  float4 fo;
  fo.x = (o0 - mean2) * rstd2 * s3v.x + b3v.x;
  fo.y = (o1 - mean2) * rstd2 * s3v.y + b3v.y;
  fo.z = (o2 - mean2) * rstd2 * s3v.z + b3v.z;
  fo.w = (o3 - mean2) * rstd2 * s3v.w + b3v.w;
  *(float4*)&out[base] = fo;
}

// ------------------------------------------------------------------ launch
extern "C" void kernel_launch(void* const* d_in, const int* in_sizes, int n_in,
                              void* d_out, int out_size, void* d_ws, size_t ws_size,
                              hipStream_t stream) {
  (void)in_sizes; (void)n_in; (void)out_size; (void)ws_size;
  const float* x   = (const float*)d_in[0];
  const float* msk = (const float*)d_in[1];
  const float* wq  = (const float*)d_in[2];
  const float* wk  = (const float*)d_in[3];
  const float* wv  = (const float*)d_in[4];
  const float* w1  = (const float*)d_in[5];
  const float* b1  = (const float*)d_in[6];
  const float* w2  = (const float*)d_in[7];
  const float* b2  = (const float*)d_in[8];
  const float* l1s = (const float*)d_in[9];
  const float* l1b = (const float*)d_in[10];
  const float* l2s = (const float*)d_in[11];
  const float* l2b = (const float*)d_in[12];
  const float* l3s = (const float*)d_in[13];
  const float* l3b = (const float*)d_in[14];
  float* outp = (float*)d_out;

  char* ws = (char*)d_ws;
  unsigned short* xb   = (unsigned short*)(ws);                       // 8 MB
  unsigned short* wt   = (unsigned short*)(ws + ((size_t)8  << 20));  // 10 MB
  unsigned short* Qb   = (unsigned short*)(ws + ((size_t)18 << 20));  // 8 MB [B,H,T,DH]
  unsigned short* Kb   = (unsigned short*)(ws + ((size_t)26 << 20));  // 8 MB
  _Float16*       Vtg  = (_Float16*)(ws + ((size_t)34 << 20));        // 8 MB k-shuffled V^T
  unsigned short* attn = (unsigned short*)(ws + ((size_t)42 << 20));  // 8 MB bf16 [B,T,D]
  float* h1            = (float*)(ws + ((size_t)50 << 20));           // 16 MB
  unsigned short* h1b  = (unsigned short*)(ws + ((size_t)18 << 20));  // reuse Qb
  unsigned short* gb   = (unsigned short*)(ws + ((size_t)26 << 20));  // reuse Kb
  float* ffn           = (float*)(ws + ((size_t)34 << 20));           // reuse Vtg+attn

  cast_x_kernel<<<4096, 256, 0, stream>>>((const float4*)x, xb);
  transpose_cast_w<<<dim3(16, 16, 5), 256, 0, stream>>>(wq, wk, wv, w1, w2, wt);
  gemm_qkv<<<dim3(24, 32), 256, 0, stream>>>(xb, wt, Qb, Kb, Vtg);
  flash_attn<<<512, 256, 0, stream>>>(Qb, Kb, Vtg, msk, attn);
  last_row_kernel<<<dim3(16, 4), 256, 0, stream>>>(Qb, Kb, Vtg, msk, attn);
  ln_res_kernel<<<4096, 256, 0, stream>>>(x, attn, l1s, l1b, h1, h1b);
  gemm_ffn<1><<<dim3(8, 64), 256, 0, stream>>>(h1b, wt + (size_t)3 * 1024 * 1024, gb, nullptr, b1);
  gemm_ffn<2><<<dim3(8, 64), 256, 0, stream>>>(gb, wt + (size_t)4 * 1024 * 1024, nullptr, ffn, b2);
  ln_double_kernel<<<4096, 256, 0, stream>>>(h1, ffn, l2s, l2b, l3s, l3b, outp);
}

// Round 6
// 264.537 us; speedup vs baseline: 1.0958x; 1.0434x over previous
//
#include <hip/hip_runtime.h>
#include <stdint.h>

// B=4, T=1024, D=1024, H=16, DH=64. fp32 in/out, absmax thr 0.1.
// R6 vs R5:
//  - gemm_qkv: V epilogue staged through LDS (Cs[2][64][136]) -> fully
//    coalesced uint4 global stores of the k-shuffled V^T layout (was 64
//    scattered 2B stores/thread with 2KB lane stride).
//  - cast_x + transpose_cast_w merged into one prep kernel (one less gap).
//  - flash: exp folded to native exp2f with combined constant (one mul less
//    per score element); mask shift -14427 in log2 domain (same exact 0).

#define B_  4
#define T_  1024
#define D_  1024
#define H_  16
#define DH_ 64

typedef __attribute__((ext_vector_type(8))) short short8;
typedef __attribute__((ext_vector_type(4))) float floatx4;
typedef __attribute__((ext_vector_type(4))) _Float16 half4;

__device__ __forceinline__ unsigned short f2bf(float f) {
  union { float f; uint32_t u; } a; a.f = f;
  uint32_t r = a.u + 0x7FFFu + ((a.u >> 16) & 1u);
  return (unsigned short)(r >> 16);
}
__device__ __forceinline__ float bf2f(unsigned short u) {
  union { uint32_t u; float f; } a; a.u = ((uint32_t)u) << 16;
  return a.f;
}

#define GLD_LDS16(g, l) __builtin_amdgcn_global_load_lds( \
    (const __attribute__((address_space(1))) unsigned int*)(g), \
    (__attribute__((address_space(3))) unsigned int*)(l), 16, 0, 0)

// ---------------------------------------------- prep: cast x + transpose W
// blocks [0,4096): cast x fp32->bf16. blocks [4096,5376): transpose+cast W.
__global__ __launch_bounds__(256)
void prep_kernel(const float4* __restrict__ x4, unsigned short* __restrict__ xb,
                 const float* __restrict__ w0, const float* __restrict__ w1,
                 const float* __restrict__ w2, const float* __restrict__ w3,
                 const float* __restrict__ w4, unsigned short* __restrict__ dst_all) {
  const int t = threadIdx.x;
  if (blockIdx.x < 4096) {
    int idx = blockIdx.x * 256 + t;
    float4 v = x4[idx];
    union { uint2 u; unsigned short s[4]; } o;
    o.s[0] = f2bf(v.x); o.s[1] = f2bf(v.y); o.s[2] = f2bf(v.z); o.s[3] = f2bf(v.w);
    *(uint2*)&xb[(size_t)idx * 4] = o.u;
    return;
  }
  const int b = blockIdx.x - 4096;
  const int z = b >> 8, ky = (b >> 4) & 15, nx = b & 15;
  const float* src = (z == 0) ? w0 : (z == 1) ? w1 : (z == 2) ? w2 : (z == 3) ? w3 : w4;
  unsigned short* dst = dst_all + (size_t)z * D_ * D_;
  __shared__ __align__(16) unsigned short tile[64 * 72];
  const int k0 = ky * 64, n0 = nx * 64;
#pragma unroll
  for (int c = 0; c < 4; ++c) {
    int idx = c * 256 + t;
    int r = idx >> 4, cc = (idx & 15) << 2;
    float4 v = *(const float4*)&src[(size_t)(k0 + r) * D_ + n0 + cc];
    tile[(cc + 0) * 72 + r] = f2bf(v.x);
    tile[(cc + 1) * 72 + r] = f2bf(v.y);
    tile[(cc + 2) * 72 + r] = f2bf(v.z);
    tile[(cc + 3) * 72 + r] = f2bf(v.w);
  }
  __syncthreads();
  int rr = t >> 2, ck = (t & 3) << 4;
  uint4 v0 = *(const uint4*)&tile[rr * 72 + ck];
  uint4 v1 = *(const uint4*)&tile[rr * 72 + ck + 8];
  *(uint4*)&dst[(size_t)(n0 + rr) * D_ + k0 + ck] = v0;
  *(uint4*)&dst[(size_t)(n0 + rr) * D_ + k0 + ck + 8] = v1;
}

// ------------------------------------------------------------------ QKV GEMM
// 128x128 tile, BK=32, global_load_lds. Q,K bf16 -> [B,H,T,DH] (direct, 32B
// chunked). V fp16 -> k-shuffled V^T [d][kb][quad][j][r], staged via LDS for
// fully coalesced stores.
__global__ __launch_bounds__(256, 2)
void gemm_qkv(const unsigned short* __restrict__ A,
              const unsigned short* __restrict__ Bt,
              unsigned short* __restrict__ oQ, unsigned short* __restrict__ oK,
              _Float16* __restrict__ oV) {
  const int K = 1024;
  __shared__ __align__(16) unsigned short As[128 * 32];
  __shared__ __align__(16) unsigned short Bs[128 * 32];
  __shared__ __align__(16) _Float16 Cs[2 * 64 * 136];   // V-block epilogue staging
  const int t = threadIdx.x;
  const int lane = t & 63, w = t >> 6;
  const int quad = lane >> 4, lm = lane & 15;
  const int wm = w >> 1, wn = w & 1;
  const int m0 = blockIdx.y * 128, n0 = blockIdx.x * 128;
  const int arow = w * 32 + (lane >> 2), acol = (lane & 3) << 3;

  floatx4 acc[4][4];
#pragma unroll
  for (int i = 0; i < 4; ++i)
#pragma unroll
    for (int j = 0; j < 4; ++j) acc[i][j] = (floatx4){0.f, 0.f, 0.f, 0.f};

  for (int kt = 0; kt < K; kt += 32) {
    const unsigned short* ga = A + (size_t)(m0 + arow) * K + kt + acol;
    const unsigned short* gb = Bt + (size_t)(n0 + arow) * K + kt + acol;
    GLD_LDS16(ga, &As[(w * 32) * 32]);
    GLD_LDS16(ga + (size_t)16 * K, &As[(w * 32 + 16) * 32]);
    GLD_LDS16(gb, &Bs[(w * 32) * 32]);
    GLD_LDS16(gb + (size_t)16 * K, &Bs[(w * 32 + 16) * 32]);
    __syncthreads();
    short8 a[4], b[4];
#pragma unroll
    for (int i = 0; i < 4; ++i) a[i] = *(const short8*)&As[(wm * 64 + i * 16 + lm) * 32 + quad * 8];
#pragma unroll
    for (int j = 0; j < 4; ++j) b[j] = *(const short8*)&Bs[(wn * 64 + j * 16 + lm) * 32 + quad * 8];
#pragma unroll
    for (int i = 0; i < 4; ++i)
#pragma unroll
      for (int j = 0; j < 4; ++j)
        acc[i][j] = __builtin_amdgcn_mfma_f32_16x16x32_bf16(a[i], b[j], acc[i][j], 0, 0, 0);
    __syncthreads();
  }

  if (n0 < 2048) {
    // Q or K block: direct stores (lanes -> 16 consecutive dd = 32B chunks)
    unsigned short* p = (n0 < 1024) ? oQ : oK;
#pragma unroll
    for (int i = 0; i < 4; ++i) {
      int gmb = m0 + wm * 64 + i * 16 + quad * 4;
#pragma unroll
      for (int j = 0; j < 4; ++j) {
        int gn = n0 + wn * 64 + j * 16 + lm;
        int nn = gn & 1023, hh = nn >> 6, dd = nn & 63;
#pragma unroll
        for (int r = 0; r < 4; ++r) {
          int gm = gmb + r;
          int bb = gm >> 10, tt = gm & 1023;
          p[(((size_t)bb * H_ + hh) * T_ + tt) * DH_ + dd] = f2bf(acc[i][j][r]);
        }
      }
    }
  } else {
    // V block: stage k-shuffled tile in LDS, then coalesced uint4 stores.
    // tt&127 = wm*64+i*16+quad*4+r -> (jj=wm*4+i, qd=quad, rr=r);
    // kperm = quad*32 + (wm*4+i)*4 + r  (r contiguous -> one 8B write).
#pragma unroll
    for (int i = 0; i < 4; ++i) {
#pragma unroll
      for (int j = 0; j < 4; ++j) {
        int gn = n0 + wn * 64 + j * 16 + lm;
        int hd = (gn >> 6) & 1, dd = gn & 63;
        int kperm = quad * 32 + (wm * 4 + i) * 4;
        union { _Float16 h[4]; uint2 u; } pk;
#pragma unroll
        for (int r = 0; r < 4; ++r) pk.h[r] = (_Float16)acc[i][j][r];
        *(uint2*)&Cs[((size_t)(hd * 64 + dd)) * 136 + kperm] = pk.u;
      }
    }
    __syncthreads();
    const int row = t >> 1, half = t & 1;
    const int hd = row >> 6, dd = row & 63;
    const int hh = ((n0 & 1023) >> 6) + hd;
    const int bb = m0 >> 10, kbg = (m0 >> 7) & 7;
    const _Float16* srcp = &Cs[(size_t)(hd * 64 + dd) * 136 + half * 64];
    _Float16* dstp = oV + ((((size_t)bb * H_ + hh) * DH_ + dd) * 8 + kbg) * 128 + half * 64;
#pragma unroll
    for (int g = 0; g < 8; ++g)
      *(uint4*)(dstp + g * 8) = *(const uint4*)(srcp + g * 8);
  }
}

// ------------------------------------------------------------ FFN GEMM 64x128
template <int MODE>
__global__ __launch_bounds__(256, 2)
void gemm_ffn(const unsigned short* __restrict__ A,
              const unsigned short* __restrict__ Bt,
              unsigned short* __restrict__ oBf, float* __restrict__ oF,
              const float* __restrict__ bias) {
  const int K = 1024, N = 1024;
  __shared__ __align__(16) unsigned short As[64 * 32];
  __shared__ __align__(16) unsigned short Bs[128 * 32];
  const int t = threadIdx.x;
  const int lane = t & 63, w = t >> 6;
  const int quad = lane >> 4, lm = lane & 15;
  const int wm = w >> 1, wn = w & 1;
  const int m0 = blockIdx.y * 64, n0 = blockIdx.x * 128;
  const int lrow = lane >> 2, lcol = (lane & 3) << 3;

  floatx4 acc[2][4];
#pragma unroll
  for (int i = 0; i < 2; ++i)
#pragma unroll
    for (int j = 0; j < 4; ++j) acc[i][j] = (floatx4){0.f, 0.f, 0.f, 0.f};

  for (int kt = 0; kt < K; kt += 32) {
    const unsigned short* ga = A + (size_t)(m0 + w * 16 + lrow) * K + kt + lcol;
    const unsigned short* gb = Bt + (size_t)(n0 + w * 32 + lrow) * K + kt + lcol;
    GLD_LDS16(ga, &As[(w * 16) * 32]);
    GLD_LDS16(gb, &Bs[(w * 32) * 32]);
    GLD_LDS16(gb + (size_t)16 * K, &Bs[(w * 32 + 16) * 32]);
    __syncthreads();
    short8 a[2], b[4];
#pragma unroll
    for (int i = 0; i < 2; ++i) a[i] = *(const short8*)&As[(wm * 32 + i * 16 + lm) * 32 + quad * 8];
#pragma unroll
    for (int j = 0; j < 4; ++j) b[j] = *(const short8*)&Bs[(wn * 64 + j * 16 + lm) * 32 + quad * 8];
#pragma unroll
    for (int i = 0; i < 2; ++i)
#pragma unroll
      for (int j = 0; j < 4; ++j)
        acc[i][j] = __builtin_amdgcn_mfma_f32_16x16x32_bf16(a[i], b[j], acc[i][j], 0, 0, 0);
    __syncthreads();
  }

#pragma unroll
  for (int i = 0; i < 2; ++i) {
    int gmb = m0 + wm * 32 + i * 16 + quad * 4;
#pragma unroll
    for (int j = 0; j < 4; ++j) {
      int gn = n0 + wn * 64 + j * 16 + lm;
      float bv = bias[gn];
#pragma unroll
      for (int r = 0; r < 4; ++r) {
        int gm = gmb + r;
        float v = acc[i][j][r] + bv;
        if (MODE == 1) {
          oBf[(size_t)gm * N + gn] = f2bf(fmaxf(v, 0.f));
        } else {
          oF[(size_t)gm * N + gn] = v;
        }
      }
    }
  }
}

// --------------------------------------------------------------- flash attn
// 512 blocks x 256 thr; each wave independent, NO LDS. Per k-block all K/V
// fragments bulk-loaded into registers, then 8 j-steps of S^T-mfma ->
// log2-domain softmax (native exp2) -> in-register PV (mfma_16x16x16_f16).
__global__ __launch_bounds__(256, 2)
void flash_attn(const unsigned short* __restrict__ Qb,
                const unsigned short* __restrict__ Kb,
                const _Float16* __restrict__ Vtg,
                const float* __restrict__ maskp,
                unsigned short* __restrict__ attn) {
  const int t = threadIdx.x;
  const int lane = t & 63, w = t >> 6;
  const int quad = lane >> 4, lm = lane & 15;

  const int bid = blockIdx.x;
  const int hi = bid >> 8, lo = bid & 255;
  const int qraw = lo & 7;
  const int qb = hi ? (7 - qraw) : qraw;
  const int hb = (lo >> 3) | (hi << 5);
  const int hh = hb & 15, bb = hb >> 4;
  const int q0 = qb << 7;

  const size_t headoff = ((size_t)bb * H_ + hh) * T_ * DH_;
  const unsigned short* Qh = Qb + headoff;
  const unsigned short* Kh = Kb + headoff;
  const _Float16* Vh = Vtg + headoff;   // k-shuffled [d][kb][quad][j][r]

  short8 qf[2][2];
#pragma unroll
  for (int qg = 0; qg < 2; ++qg)
#pragma unroll
    for (int ks = 0; ks < 2; ++ks)
      qf[qg][ks] = *(const short8*)(Qh + (size_t)(q0 + w * 32 + qg * 16 + lm) * 64 + ks * 32 + quad * 8);

  float lsum[2] = {0.f, 0.f};
  floatx4 acc[2][4];
#pragma unroll
  for (int qg = 0; qg < 2; ++qg)
#pragma unroll
    for (int j2 = 0; j2 < 4; ++j2) acc[qg][j2] = (floatx4){0.f, 0.f, 0.f, 0.f};

  const int qglob0 = q0 + w * 32 + lm;
  const float C1 = 0.18033688f;          // 0.125 * log2(e)
  const float MSHIFT = 14426.950408f;    // 10000 * 1.4426950408

  for (int kb = qb; kb < 8; ++kb) {
    const int k0 = kb * 128;
    const bool need_mask = (kb == qb);
    const unsigned short* Kblk = Kh + (size_t)k0 * 64;

    short8 kf[8][2];
#pragma unroll
    for (int j = 0; j < 8; ++j) {
      kf[j][0] = *(const short8*)(Kblk + (size_t)(j * 16 + lm) * 64 + quad * 8);
      kf[j][1] = *(const short8*)(Kblk + (size_t)(j * 16 + lm) * 64 + 32 + quad * 8);
    }
    union { uint4 u[4]; _Float16 h[32]; } vf[4];
#pragma unroll
    for (int j2 = 0; j2 < 4; ++j2) {
      const _Float16* vp = Vh + ((size_t)(j2 * 16 + lm) * 8 + kb) * 128 + quad * 32;
#pragma unroll
      for (int g = 0; g < 4; ++g) vf[j2].u[g] = *(const uint4*)(vp + g * 8);
    }

#pragma unroll
    for (int j = 0; j < 8; ++j) {
      floatx4 st[2];
#pragma unroll
      for (int qg = 0; qg < 2; ++qg) {
        floatx4 z = (floatx4){0.f, 0.f, 0.f, 0.f};
        z = __builtin_amdgcn_mfma_f32_16x16x32_bf16(kf[j][0], qf[qg][0], z, 0, 0, 0);
        st[qg] = __builtin_amdgcn_mfma_f32_16x16x32_bf16(kf[j][1], qf[qg][1], z, 0, 0, 0);
      }
      half4 pa[2];
#pragma unroll
      for (int qg = 0; qg < 2; ++qg) {
        const int qg_q = qglob0 + qg * 16;
#pragma unroll
        for (int r = 0; r < 4; ++r) {
          int kg = k0 + j * 16 + quad * 4 + r;
          float v = st[qg][r] * C1;
          if (need_mask && kg <= qg_q) v -= MSHIFT;
          float p = exp2f(v);
          lsum[qg] += p;
          pa[qg][r] = (_Float16)p;
        }
      }
#pragma unroll
      for (int j2 = 0; j2 < 4; ++j2) {
        half4 vb;
#pragma unroll
        for (int r = 0; r < 4; ++r) vb[r] = vf[j2].h[j * 4 + r];
        acc[0][j2] = __builtin_amdgcn_mfma_f32_16x16x16f16(pa[0], vb, acc[0][j2], 0, 0, 0);
        acc[1][j2] = __builtin_amdgcn_mfma_f32_16x16x16f16(pa[1], vb, acc[1][j2], 0, 0, 0);
      }
    }
  }

#pragma unroll
  for (int qg = 0; qg < 2; ++qg) {
    float l = lsum[qg];
    l += __shfl_xor(l, 16);
    l += __shfl_xor(l, 32);
    float s = maskp[bb * T_ + qglob0 + qg * 16] / l;
#pragma unroll
    for (int r = 0; r < 4; ++r) {
      float bsc = __shfl(s, quad * 4 + r);
      int tq = q0 + w * 32 + qg * 16 + quad * 4 + r;
#pragma unroll
      for (int j2 = 0; j2 < 4; ++j2)
        attn[((size_t)(bb * T_ + tq)) * D_ + hh * 64 + j2 * 16 + lm] = f2bf(acc[qg][j2][r] * bsc);
    }
  }
}

// ------------------------------------------------- row 1023 exact softmax fix
__global__ __launch_bounds__(256)
void last_row_kernel(const unsigned short* __restrict__ Qb,
                     const unsigned short* __restrict__ Kb,
                     const _Float16* __restrict__ Vtg,
                     const float* __restrict__ maskp,
                     unsigned short* __restrict__ attn) {
  const int hh = blockIdx.x, bb = blockIdx.y;
  const size_t headoff = ((size_t)bb * H_ + hh) * T_ * DH_;
  const unsigned short* Qh = Qb + headoff;
  const unsigned short* Kh = Kb + headoff;
  const _Float16* Vh = Vtg + headoff;   // k-shuffled
  __shared__ float qrow[64];
  __shared__ float ps[1024];
  __shared__ float red[256];
  const int t = threadIdx.x;
  if (t < 64) qrow[t] = bf2f(Qh[(size_t)1023 * 64 + t]);
  __syncthreads();
  float lp = 0.f;
#pragma unroll
  for (int c = 0; c < 4; ++c) {
    int key = c * 256 + t;
    const unsigned short* kr = Kh + (size_t)key * 64;
    float dot = 0.f;
#pragma unroll
    for (int d8 = 0; d8 < 8; ++d8) {
      union { uint4 q; unsigned short s[8]; } kk;
      kk.q = *(const uint4*)&kr[d8 * 8];
#pragma unroll
      for (int u = 0; u < 8; ++u) dot += qrow[d8 * 8 + u] * bf2f(kk.s[u]);
    }
    float p = __expf(dot * 0.125f);
    ps[key] = p;
    lp += p;
  }
  red[t] = lp;
  __syncthreads();
  for (int s = 128; s > 0; s >>= 1) {
    if (t < s) red[t] += red[t + s];
    __syncthreads();
  }
  float ltot = red[0];
  __syncthreads();
  const int d = t & 63, part = t >> 6;
  const _Float16* vr = Vh + (size_t)d * 1024 + part * 256;
  float acc = 0.f;
#pragma unroll
  for (int c = 0; c < 32; ++c) {
    union { uint4 q; _Float16 h[8]; } vv;
    vv.q = *(const uint4*)&vr[c * 8];
#pragma unroll
    for (int u = 0; u < 8; ++u) {
      int si = part * 256 + c * 8 + u;       // storage index
      int jj = (si >> 2) & 7, qd = (si >> 5) & 3, rr2 = si & 3;
      int kk = (si & ~127) + jj * 16 + qd * 4 + rr2;
      acc += ps[kk] * (float)vv.h[u];
    }
  }
  red[t] = acc;
  __syncthreads();
  if (t < 64) {
    float tot = red[t] + red[t + 64] + red[t + 128] + red[t + 192];
    attn[((size_t)(bb * T_ + 1023)) * D_ + hh * 64 + t] =
        f2bf(tot / ltot * maskp[bb * T_ + 1023]);
  }
}

// --------------------------------------------- LN(x + attn_bf16) -> h1 f32+bf16
__global__ __launch_bounds__(256)
void ln_res_kernel(const float* __restrict__ xa, const unsigned short* __restrict__ attn,
                   const float* __restrict__ sc, const float* __restrict__ bi,
                   float* __restrict__ h, unsigned short* __restrict__ hb) {
  const int row = blockIdx.x, t = threadIdx.x;
  const int lane = t & 63, wid = t >> 6;
  size_t base = (size_t)row * D_ + t * 4;
  float4 a = *(const float4*)&xa[base];
  union { uint2 u; unsigned short s[4]; } au;
  au.u = *(const uint2*)&attn[base];
  float v0 = a.x + bf2f(au.s[0]), v1 = a.y + bf2f(au.s[1]);
  float v2 = a.z + bf2f(au.s[2]), v3 = a.w + bf2f(au.s[3]);
  float s1 = v0 + v1 + v2 + v3;
  float s2 = v0 * v0 + v1 * v1 + v2 * v2 + v3 * v3;
#pragma unroll
  for (int off = 32; off; off >>= 1) { s1 += __shfl_down(s1, off); s2 += __shfl_down(s2, off); }
  __shared__ float r1[4], r2[4];
  if (lane == 0) { r1[wid] = s1; r2[wid] = s2; }
  __syncthreads();
  s1 = r1[0] + r1[1] + r1[2] + r1[3];
  s2 = r2[0] + r2[1] + r2[2] + r2[3];
  float mean = s1 * (1.f / 1024.f);
  float var = s2 * (1.f / 1024.f) - mean * mean;
  float rstd = rsqrtf(var + 1e-5f);
  float4 sv = *(const float4*)&sc[t * 4];
  float4 bv = *(const float4*)&bi[t * 4];
  float o0 = (v0 - mean) * rstd * sv.x + bv.x;
  float o1 = (v1 - mean) * rstd * sv.y + bv.y;
  float o2 = (v2 - mean) * rstd * sv.z + bv.z;
  float o3 = (v3 - mean) * rstd * sv.w + bv.w;
  float4 ov = {o0, o1, o2, o3};
  *(float4*)&h[base] = ov;
  union { uint2 u; unsigned short s[4]; } ob;
  ob.s[0] = f2bf(o0); ob.s[1] = f2bf(o1); ob.s[2] = f2bf(o2); ob.s[3] = f2bf(o3);
  *(uint2*)&hb[base] = ob.u;
}

// --------------------------------------- out = LN(LN(h1+ffn,ln2),ln3)
__global__ __launch_bounds__(256)
void ln_double_kernel(const float* __restrict__ h1, const float* __restrict__ ffn,
                      const float* __restrict__ s2c, const float* __restrict__ b2c,
                      const float* __restrict__ s3c, const float* __restrict__ b3c,
                      float* __restrict__ out) {
  const int row = blockIdx.x, t = threadIdx.x;
  const int lane = t & 63, wid = t >> 6;
  size_t base = (size_t)row * D_ + t * 4;
  float4 a = *(const float4*)&h1[base];
  float4 b = *(const float4*)&ffn[base];
  float v0 = a.x + b.x, v1 = a.y + b.y, v2 = a.z + b.z, v3 = a.w + b.w;
  float s1 = v0 + v1 + v2 + v3;
  float s2 = v0 * v0 + v1 * v1 + v2 * v2 + v3 * v3;
#pragma unroll
  for (int off = 32; off; off >>= 1) { s1 += __shfl_down(s1, off); s2 += __shfl_down(s2, off); }
  __shared__ float ra[4], rb[4], rc[4], rd[4];
  if (lane == 0) { ra[wid] = s1; rb[wid] = s2; }
  __syncthreads();
  s1 = ra[0] + ra[1] + ra[2] + ra[3];
  s2 = rb[0] + rb[1] + rb[2] + rb[3];
  float mean = s1 * (1.f / 1024.f);
  float var = s2 * (1.f / 1024.f) - mean * mean;
  float rstd = rsqrtf(var + 1e-5f);
  float4 sv = *(const float4*)&s2c[t * 4];
  float4 bv = *(const float4*)&b2c[t * 4];
  float o0 = (v0 - mean) * rstd * sv.x + bv.x;
  float o1 = (v1 - mean) * rstd * sv.y + bv.y;
  float o2 = (v2 - mean) * rstd * sv.z + bv.z;
  float o3 = (v3 - mean) * rstd * sv.w + bv.w;
  float u1 = o0 + o1 + o2 + o3;
  float u2 = o0 * o0 + o1 * o1 + o2 * o2 + o3 * o3;
#pragma unroll
  for (int off = 32; off; off >>= 1) { u1 += __shfl_down(u1, off); u2 += __shfl_down(u2, off); }
  if (lane == 0) { rc[wid] = u1; rd[wid] = u2; }
  __syncthreads();
  u1 = rc[0] + rc[1] + rc[2] + rc[3];
  u2 = rd[0] + rd[1] + rd[2] + rd[3];
  float mean2 = u1 * (1.f / 1024.f);
  float var2 = u2 * (1.f / 1024.f) - mean2 * mean2;
  float rstd2 = rsqrtf(var2 + 1e-5f);
  float4 s3v = *(const float4*)&s3c[t * 4];
  float4 b3v = *(const float4*)&b3c[t * 4];
  float4 fo;
  fo.x = (o0 - mean2) * rstd2 * s3v.x + b3v.x;
  fo.y = (o1 - mean2) * rstd2 * s3v.y + b3v.y;
  fo.z = (o2 - mean2) * rstd2 * s3v.z + b3v.z;
  fo.w = (o3 - mean2) * rstd2 * s3v.w + b3v.w;
  *(float4*)&out[base] = fo;
}

// ------------------------------------------------------------------ launch
extern "C" void kernel_launch(void* const* d_in, const int* in_sizes, int n_in,
                              void* d_out, int out_size, void* d_ws, size_t ws_size,
                              hipStream_t stream) {
  (void)in_sizes; (void)n_in; (void)out_size; (void)ws_size;
  const float* x   = (const float*)d_in[0];
  const float* msk = (const float*)d_in[1];
  const float* wq  = (const float*)d_in[2];
  const float* wk  = (const float*)d_in[3];
  const float* wv  = (const float*)d_in[4];
  const float* w1  = (const float*)d_in[5];
  const float* b1  = (const float*)d_in[6];
  const float* w2  = (const float*)d_in[7];
  const float* b2  = (const float*)d_in[8];
  const float* l1s = (const float*)d_in[9];
  const float* l1b = (const float*)d_in[10];
  const float* l2s = (const float*)d_in[11];
  const float* l2b = (const float*)d_in[12];
  const float* l3s = (const float*)d_in[13];
  const float* l3b = (const float*)d_in[14];
  float* outp = (float*)d_out;

  char* ws = (char*)d_ws;
  unsigned short* xb   = (unsigned short*)(ws);                       // 8 MB
  unsigned short* wt   = (unsigned short*)(ws + ((size_t)8  << 20));  // 10 MB
  unsigned short* Qb   = (unsigned short*)(ws + ((size_t)18 << 20));  // 8 MB [B,H,T,DH]
  unsigned short* Kb   = (unsigned short*)(ws + ((size_t)26 << 20));  // 8 MB
  _Float16*       Vtg  = (_Float16*)(ws + ((size_t)34 << 20));        // 8 MB k-shuffled V^T
  unsigned short* attn = (unsigned short*)(ws + ((size_t)42 << 20));  // 8 MB bf16 [B,T,D]
  float* h1            = (float*)(ws + ((size_t)50 << 20));           // 16 MB
  unsigned short* h1b  = (unsigned short*)(ws + ((size_t)18 << 20));  // reuse Qb
  unsigned short* gb   = (unsigned short*)(ws + ((size_t)26 << 20));  // reuse Kb
  float* ffn           = (float*)(ws + ((size_t)34 << 20));           // reuse Vtg+attn

  prep_kernel<<<4096 + 1280, 256, 0, stream>>>((const float4*)x, xb,
                                               wq, wk, wv, w1, w2, wt);
  gemm_qkv<<<dim3(24, 32), 256, 0, stream>>>(xb, wt, Qb, Kb, Vtg);
  flash_attn<<<512, 256, 0, stream>>>(Qb, Kb, Vtg, msk, attn);
  last_row_kernel<<<dim3(16, 4), 256, 0, stream>>>(Qb, Kb, Vtg, msk, attn);
  ln_res_kernel<<<4096, 256, 0, stream>>>(x, attn, l1s, l1b, h1, h1b);
  gemm_ffn<1><<<dim3(8, 64), 256, 0, stream>>>(h1b, wt + (size_t)3 * 1024 * 1024, gb, nullptr, b1);
  gemm_ffn<2><<<dim3(8, 64), 256, 0, stream>>>(gb, wt + (size_t)4 * 1024 * 1024, nullptr, ffn, b2);
  ln_double_kernel<<<4096, 256, 0, stream>>>(h1, ffn, l2s, l2b, l3s, l3b, outp);
}

// Round 7
// 258.387 us; speedup vs baseline: 1.1219x; 1.0238x over previous
//
#include <hip/hip_runtime.h>
#include <stdint.h>

// B=4, T=1024, D=1024, H=16, DH=64. fp32 in/out, absmax thr 0.1.
// R7 vs R6:
//  - flash: intra-iteration K-prefetch rotation (S-MFMAs consume kf, then
//    next kb's K loads are issued into the same regs -> full softmax+PV
//    window to hide latency). V loads at iter top (hidden by S+softmax).
//  - Q pre-scaled by 0.125*log2e in QKV epilogue (flash softmax is exp2
//    of the raw MFMA result; mask shift stays -14426.95 = exact 0).
//  - row-1023 fix fused into flash (wave 3 of qb==7 blocks loops kb=0..7,
//    row 1023 never masked -> full raw softmax; rows 992..1022 get exact-0
//    contributions from kb<7). last_row_kernel deleted.

#define B_  4
#define T_  1024
#define D_  1024
#define H_  16
#define DH_ 64

typedef __attribute__((ext_vector_type(8))) short short8;
typedef __attribute__((ext_vector_type(4))) float floatx4;
typedef __attribute__((ext_vector_type(4))) _Float16 half4;

__device__ __forceinline__ unsigned short f2bf(float f) {
  union { float f; uint32_t u; } a; a.f = f;
  uint32_t r = a.u + 0x7FFFu + ((a.u >> 16) & 1u);
  return (unsigned short)(r >> 16);
}
__device__ __forceinline__ float bf2f(unsigned short u) {
  union { uint32_t u; float f; } a; a.u = ((uint32_t)u) << 16;
  return a.f;
}

#define GLD_LDS16(g, l) __builtin_amdgcn_global_load_lds( \
    (const __attribute__((address_space(1))) unsigned int*)(g), \
    (__attribute__((address_space(3))) unsigned int*)(l), 16, 0, 0)

// ---------------------------------------------- prep: cast x + transpose W
__global__ __launch_bounds__(256)
void prep_kernel(const float4* __restrict__ x4, unsigned short* __restrict__ xb,
                 const float* __restrict__ w0, const float* __restrict__ w1,
                 const float* __restrict__ w2, const float* __restrict__ w3,
                 const float* __restrict__ w4, unsigned short* __restrict__ dst_all) {
  const int t = threadIdx.x;
  if (blockIdx.x < 4096) {
    int idx = blockIdx.x * 256 + t;
    float4 v = x4[idx];
    union { uint2 u; unsigned short s[4]; } o;
    o.s[0] = f2bf(v.x); o.s[1] = f2bf(v.y); o.s[2] = f2bf(v.z); o.s[3] = f2bf(v.w);
    *(uint2*)&xb[(size_t)idx * 4] = o.u;
    return;
  }
  const int b = blockIdx.x - 4096;
  const int z = b >> 8, ky = (b >> 4) & 15, nx = b & 15;
  const float* src = (z == 0) ? w0 : (z == 1) ? w1 : (z == 2) ? w2 : (z == 3) ? w3 : w4;
  unsigned short* dst = dst_all + (size_t)z * D_ * D_;
  __shared__ __align__(16) unsigned short tile[64 * 72];
  const int k0 = ky * 64, n0 = nx * 64;
#pragma unroll
  for (int c = 0; c < 4; ++c) {
    int idx = c * 256 + t;
    int r = idx >> 4, cc = (idx & 15) << 2;
    float4 v = *(const float4*)&src[(size_t)(k0 + r) * D_ + n0 + cc];
    tile[(cc + 0) * 72 + r] = f2bf(v.x);
    tile[(cc + 1) * 72 + r] = f2bf(v.y);
    tile[(cc + 2) * 72 + r] = f2bf(v.z);
    tile[(cc + 3) * 72 + r] = f2bf(v.w);
  }
  __syncthreads();
  int rr = t >> 2, ck = (t & 3) << 4;
  uint4 v0 = *(const uint4*)&tile[rr * 72 + ck];
  uint4 v1 = *(const uint4*)&tile[rr * 72 + ck + 8];
  *(uint4*)&dst[(size_t)(n0 + rr) * D_ + k0 + ck] = v0;
  *(uint4*)&dst[(size_t)(n0 + rr) * D_ + k0 + ck + 8] = v1;
}

// ------------------------------------------------------------------ QKV GEMM
// Q pre-scaled by 0.125*log2(e); Q,K bf16 -> [B,H,T,DH]; V fp16 k-shuffled
// V^T [d][kb][quad][j][r] staged via LDS for coalesced stores.
__global__ __launch_bounds__(256, 2)
void gemm_qkv(const unsigned short* __restrict__ A,
              const unsigned short* __restrict__ Bt,
              unsigned short* __restrict__ oQ, unsigned short* __restrict__ oK,
              _Float16* __restrict__ oV) {
  const int K = 1024;
  __shared__ __align__(16) unsigned short As[128 * 32];
  __shared__ __align__(16) unsigned short Bs[128 * 32];
  __shared__ __align__(16) _Float16 Cs[2 * 64 * 136];
  const int t = threadIdx.x;
  const int lane = t & 63, w = t >> 6;
  const int quad = lane >> 4, lm = lane & 15;
  const int wm = w >> 1, wn = w & 1;
  const int m0 = blockIdx.y * 128, n0 = blockIdx.x * 128;
  const int arow = w * 32 + (lane >> 2), acol = (lane & 3) << 3;

  floatx4 acc[4][4];
#pragma unroll
  for (int i = 0; i < 4; ++i)
#pragma unroll
    for (int j = 0; j < 4; ++j) acc[i][j] = (floatx4){0.f, 0.f, 0.f, 0.f};

  for (int kt = 0; kt < K; kt += 32) {
    const unsigned short* ga = A + (size_t)(m0 + arow) * K + kt + acol;
    const unsigned short* gb = Bt + (size_t)(n0 + arow) * K + kt + acol;
    GLD_LDS16(ga, &As[(w * 32) * 32]);
    GLD_LDS16(ga + (size_t)16 * K, &As[(w * 32 + 16) * 32]);
    GLD_LDS16(gb, &Bs[(w * 32) * 32]);
    GLD_LDS16(gb + (size_t)16 * K, &Bs[(w * 32 + 16) * 32]);
    __syncthreads();
    short8 a[4], b[4];
#pragma unroll
    for (int i = 0; i < 4; ++i) a[i] = *(const short8*)&As[(wm * 64 + i * 16 + lm) * 32 + quad * 8];
#pragma unroll
    for (int j = 0; j < 4; ++j) b[j] = *(const short8*)&Bs[(wn * 64 + j * 16 + lm) * 32 + quad * 8];
#pragma unroll
    for (int i = 0; i < 4; ++i)
#pragma unroll
      for (int j = 0; j < 4; ++j)
        acc[i][j] = __builtin_amdgcn_mfma_f32_16x16x32_bf16(a[i], b[j], acc[i][j], 0, 0, 0);
    __syncthreads();
  }

  if (n0 < 2048) {
    unsigned short* p = (n0 < 1024) ? oQ : oK;
    const float qscale = (n0 < 1024) ? 0.18033688f : 1.0f;   // 0.125*log2(e)
#pragma unroll
    for (int i = 0; i < 4; ++i) {
      int gmb = m0 + wm * 64 + i * 16 + quad * 4;
#pragma unroll
      for (int j = 0; j < 4; ++j) {
        int gn = n0 + wn * 64 + j * 16 + lm;
        int nn = gn & 1023, hh = nn >> 6, dd = nn & 63;
#pragma unroll
        for (int r = 0; r < 4; ++r) {
          int gm = gmb + r;
          int bb = gm >> 10, tt = gm & 1023;
          p[(((size_t)bb * H_ + hh) * T_ + tt) * DH_ + dd] = f2bf(acc[i][j][r] * qscale);
        }
      }
    }
  } else {
#pragma unroll
    for (int i = 0; i < 4; ++i) {
#pragma unroll
      for (int j = 0; j < 4; ++j) {
        int gn = n0 + wn * 64 + j * 16 + lm;
        int hd = (gn >> 6) & 1, dd = gn & 63;
        int kperm = quad * 32 + (wm * 4 + i) * 4;
        union { _Float16 h[4]; uint2 u; } pk;
#pragma unroll
        for (int r = 0; r < 4; ++r) pk.h[r] = (_Float16)acc[i][j][r];
        *(uint2*)&Cs[((size_t)(hd * 64 + dd)) * 136 + kperm] = pk.u;
      }
    }
    __syncthreads();
    const int row = t >> 1, half = t & 1;
    const int hd = row >> 6, dd = row & 63;
    const int hh = ((n0 & 1023) >> 6) + hd;
    const int bb = m0 >> 10, kbg = (m0 >> 7) & 7;
    const _Float16* srcp = &Cs[(size_t)(hd * 64 + dd) * 136 + half * 64];
    _Float16* dstp = oV + ((((size_t)bb * H_ + hh) * DH_ + dd) * 8 + kbg) * 128 + half * 64;
#pragma unroll
    for (int g = 0; g < 8; ++g)
      *(uint4*)(dstp + g * 8) = *(const uint4*)(srcp + g * 8);
  }
}

// ------------------------------------------------------------ FFN GEMM 64x128
template <int MODE>
__global__ __launch_bounds__(256, 2)
void gemm_ffn(const unsigned short* __restrict__ A,
              const unsigned short* __restrict__ Bt,
              unsigned short* __restrict__ oBf, float* __restrict__ oF,
              const float* __restrict__ bias) {
  const int K = 1024, N = 1024;
  __shared__ __align__(16) unsigned short As[64 * 32];
  __shared__ __align__(16) unsigned short Bs[128 * 32];
  const int t = threadIdx.x;
  const int lane = t & 63, w = t >> 6;
  const int quad = lane >> 4, lm = lane & 15;
  const int wm = w >> 1, wn = w & 1;
  const int m0 = blockIdx.y * 64, n0 = blockIdx.x * 128;
  const int lrow = lane >> 2, lcol = (lane & 3) << 3;

  floatx4 acc[2][4];
#pragma unroll
  for (int i = 0; i < 2; ++i)
#pragma unroll
    for (int j = 0; j < 4; ++j) acc[i][j] = (floatx4){0.f, 0.f, 0.f, 0.f};

  for (int kt = 0; kt < K; kt += 32) {
    const unsigned short* ga = A + (size_t)(m0 + w * 16 + lrow) * K + kt + lcol;
    const unsigned short* gb = Bt + (size_t)(n0 + w * 32 + lrow) * K + kt + lcol;
    GLD_LDS16(ga, &As[(w * 16) * 32]);
    GLD_LDS16(gb, &Bs[(w * 32) * 32]);
    GLD_LDS16(gb + (size_t)16 * K, &Bs[(w * 32 + 16) * 32]);
    __syncthreads();
    short8 a[2], b[4];
#pragma unroll
    for (int i = 0; i < 2; ++i) a[i] = *(const short8*)&As[(wm * 32 + i * 16 + lm) * 32 + quad * 8];
#pragma unroll
    for (int j = 0; j < 4; ++j) b[j] = *(const short8*)&Bs[(wn * 64 + j * 16 + lm) * 32 + quad * 8];
#pragma unroll
    for (int i = 0; i < 2; ++i)
#pragma unroll
      for (int j = 0; j < 4; ++j)
        acc[i][j] = __builtin_amdgcn_mfma_f32_16x16x32_bf16(a[i], b[j], acc[i][j], 0, 0, 0);
    __syncthreads();
  }

#pragma unroll
  for (int i = 0; i < 2; ++i) {
    int gmb = m0 + wm * 32 + i * 16 + quad * 4;
#pragma unroll
    for (int j = 0; j < 4; ++j) {
      int gn = n0 + wn * 64 + j * 16 + lm;
      float bv = bias[gn];
#pragma unroll
      for (int r = 0; r < 4; ++r) {
        int gm = gmb + r;
        float v = acc[i][j][r] + bv;
        if (MODE == 1) {
          oBf[(size_t)gm * N + gn] = f2bf(fmaxf(v, 0.f));
        } else {
          oF[(size_t)gm * N + gn] = v;
        }
      }
    }
  }
}

// --------------------------------------------------------------- flash attn
// 512 blocks x 256 thr; waves independent; no LDS. Pipelined K-prefetch:
// per kb-iter: V loads -> 16 S-MFMAs (kf dies) -> issue kb+1 K loads into kf
// -> softmax+PV. Q is pre-scaled so st is already log2-domain.
// Wave 3 of qb==7 blocks loops kb=0..7 with row 1023 never masked (fused
// last-row fix; rows 992..1022 get exact-0 from kb<7).
__global__ __launch_bounds__(256, 2)
void flash_attn(const unsigned short* __restrict__ Qb,
                const unsigned short* __restrict__ Kb,
                const _Float16* __restrict__ Vtg,
                const float* __restrict__ maskp,
                unsigned short* __restrict__ attn) {
  const int t = threadIdx.x;
  const int lane = t & 63, w = t >> 6;
  const int quad = lane >> 4, lm = lane & 15;

  const int bid = blockIdx.x;
  const int hi = bid >> 8, lo = bid & 255;
  const int qraw = lo & 7;
  const int qb = hi ? (7 - qraw) : qraw;
  const int hb = (lo >> 3) | (hi << 5);
  const int hh = hb & 15, bb = hb >> 4;
  const int q0 = qb << 7;

  const size_t headoff = ((size_t)bb * H_ + hh) * T_ * DH_;
  const unsigned short* Qh = Qb + headoff;
  const unsigned short* Kh = Kb + headoff;
  const _Float16* Vh = Vtg + headoff;   // k-shuffled [d][kb][quad][j][r]

  short8 qf[2][2];
#pragma unroll
  for (int qg = 0; qg < 2; ++qg)
#pragma unroll
    for (int ks = 0; ks < 2; ++ks)
      qf[qg][ks] = *(const short8*)(Qh + (size_t)(q0 + w * 32 + qg * 16 + lm) * 64 + ks * 32 + quad * 8);

  float lsum[2] = {0.f, 0.f};
  floatx4 acc[2][4];
#pragma unroll
  for (int qg = 0; qg < 2; ++qg)
#pragma unroll
    for (int j2 = 0; j2 < 4; ++j2) acc[qg][j2] = (floatx4){0.f, 0.f, 0.f, 0.f};

  const int qglob0 = q0 + w * 32 + lm;
  const bool excl1 = (qglob0 + 16 == 1023);   // row-1023 lane (qg=1 only)
  const float MSHIFT = 14426.950408f;          // 10000*log2(e)

  const int kb_lo = (qb == 7 && w == 3) ? 0 : qb;

  // prologue: K fragments for kb_lo
  short8 kf[8][2];
  {
    const unsigned short* Kblk = Kh + (size_t)(kb_lo * 128) * 64;
#pragma unroll
    for (int j = 0; j < 8; ++j) {
      kf[j][0] = *(const short8*)(Kblk + (size_t)(j * 16 + lm) * 64 + quad * 8);
      kf[j][1] = *(const short8*)(Kblk + (size_t)(j * 16 + lm) * 64 + 32 + quad * 8);
    }
  }

  for (int kb = kb_lo; kb < 8; ++kb) {
    const int k0 = kb * 128;
    const bool need_mask = (kb <= qb);

    // V loads for this kb (consumed in PV; hidden by S+softmax)
    union { uint4 u[4]; _Float16 h[32]; } vf[4];
#pragma unroll
    for (int j2 = 0; j2 < 4; ++j2) {
      const _Float16* vp = Vh + ((size_t)(j2 * 16 + lm) * 8 + kb) * 128 + quad * 32;
#pragma unroll
      for (int g = 0; g < 4; ++g) vf[j2].u[g] = *(const uint4*)(vp + g * 8);
    }

    // Phase A: all 16 S-MFMAs (kf regs die at issue)
    floatx4 st[8][2];
#pragma unroll
    for (int j = 0; j < 8; ++j) {
#pragma unroll
      for (int qg = 0; qg < 2; ++qg) {
        floatx4 z = (floatx4){0.f, 0.f, 0.f, 0.f};
        z = __builtin_amdgcn_mfma_f32_16x16x32_bf16(kf[j][0], qf[qg][0], z, 0, 0, 0);
        st[j][qg] = __builtin_amdgcn_mfma_f32_16x16x32_bf16(kf[j][1], qf[qg][1], z, 0, 0, 0);
      }
    }

    // Phase B: prefetch next kb's K into kf (full softmax+PV window to land)
    if (kb + 1 < 8) {
      const unsigned short* Kn = Kh + (size_t)((kb + 1) * 128) * 64;
#pragma unroll
      for (int j = 0; j < 8; ++j) {
        kf[j][0] = *(const short8*)(Kn + (size_t)(j * 16 + lm) * 64 + quad * 8);
        kf[j][1] = *(const short8*)(Kn + (size_t)(j * 16 + lm) * 64 + 32 + quad * 8);
      }
    }

    // Phase C: softmax + PV per j
#pragma unroll
    for (int j = 0; j < 8; ++j) {
      half4 pa[2];
#pragma unroll
      for (int qg = 0; qg < 2; ++qg) {
        const int qq = qglob0 + qg * 16;
        const bool skip = (qg == 1) && excl1;
#pragma unroll
        for (int r = 0; r < 4; ++r) {
          int kg = k0 + j * 16 + quad * 4 + r;
          float v = st[j][qg][r];
          if (need_mask && !skip && kg <= qq) v -= MSHIFT;
          float p = exp2f(v);
          lsum[qg] += p;
          pa[qg][r] = (_Float16)p;
        }
      }
#pragma unroll
      for (int j2 = 0; j2 < 4; ++j2) {
        half4 vb;
#pragma unroll
        for (int r = 0; r < 4; ++r) vb[r] = vf[j2].h[j * 4 + r];
        acc[0][j2] = __builtin_amdgcn_mfma_f32_16x16x16f16(pa[0], vb, acc[0][j2], 0, 0, 0);
        acc[1][j2] = __builtin_amdgcn_mfma_f32_16x16x16f16(pa[1], vb, acc[1][j2], 0, 0, 0);
      }
    }
  }

  // epilogue
#pragma unroll
  for (int qg = 0; qg < 2; ++qg) {
    float l = lsum[qg];
    l += __shfl_xor(l, 16);
    l += __shfl_xor(l, 32);
    float s = maskp[bb * T_ + qglob0 + qg * 16] / l;
#pragma unroll
    for (int r = 0; r < 4; ++r) {
      float bsc = __shfl(s, quad * 4 + r);
      int tq = q0 + w * 32 + qg * 16 + quad * 4 + r;
#pragma unroll
      for (int j2 = 0; j2 < 4; ++j2)
        attn[((size_t)(bb * T_ + tq)) * D_ + hh * 64 + j2 * 16 + lm] = f2bf(acc[qg][j2][r] * bsc);
    }
  }
}

// --------------------------------------------- LN(x + attn_bf16) -> h1 f32+bf16
__global__ __launch_bounds__(256)
void ln_res_kernel(const float* __restrict__ xa, const unsigned short* __restrict__ attn,
                   const float* __restrict__ sc, const float* __restrict__ bi,
                   float* __restrict__ h, unsigned short* __restrict__ hb) {
  const int row = blockIdx.x, t = threadIdx.x;
  const int lane = t & 63, wid = t >> 6;
  size_t base = (size_t)row * D_ + t * 4;
  float4 a = *(const float4*)&xa[base];
  union { uint2 u; unsigned short s[4]; } au;
  au.u = *(const uint2*)&attn[base];
  float v0 = a.x + bf2f(au.s[0]), v1 = a.y + bf2f(au.s[1]);
  float v2 = a.z + bf2f(au.s[2]), v3 = a.w + bf2f(au.s[3]);
  float s1 = v0 + v1 + v2 + v3;
  float s2 = v0 * v0 + v1 * v1 + v2 * v2 + v3 * v3;
#pragma unroll
  for (int off = 32; off; off >>= 1) { s1 += __shfl_down(s1, off); s2 += __shfl_down(s2, off); }
  __shared__ float r1[4], r2[4];
  if (lane == 0) { r1[wid] = s1; r2[wid] = s2; }
  __syncthreads();
  s1 = r1[0] + r1[1] + r1[2] + r1[3];
  s2 = r2[0] + r2[1] + r2[2] + r2[3];
  float mean = s1 * (1.f / 1024.f);
  float var = s2 * (1.f / 1024.f) - mean * mean;
  float rstd = rsqrtf(var + 1e-5f);
  float4 sv = *(const float4*)&sc[t * 4];
  float4 bv = *(const float4*)&bi[t * 4];
  float o0 = (v0 - mean) * rstd * sv.x + bv.x;
  float o1 = (v1 - mean) * rstd * sv.y + bv.y;
  float o2 = (v2 - mean) * rstd * sv.z + bv.z;
  float o3 = (v3 - mean) * rstd * sv.w + bv.w;
  float4 ov = {o0, o1, o2, o3};
  *(float4*)&h[base] = ov;
  union { uint2 u; unsigned short s[4]; } ob;
  ob.s[0] = f2bf(o0); ob.s[1] = f2bf(o1); ob.s[2] = f2bf(o2); ob.s[3] = f2bf(o3);
  *(uint2*)&hb[base] = ob.u;
}

// --------------------------------------- out = LN(LN(h1+ffn,ln2),ln3)
__global__ __launch_bounds__(256)
void ln_double_kernel(const float* __restrict__ h1, const float* __restrict__ ffn,
                      const float* __restrict__ s2c, const float* __restrict__ b2c,
                      const float* __restrict__ s3c, const float* __restrict__ b3c,
                      float* __restrict__ out) {
  const int row = blockIdx.x, t = threadIdx.x;
  const int lane = t & 63, wid = t >> 6;
  size_t base = (size_t)row * D_ + t * 4;
  float4 a = *(const float4*)&h1[base];
  float4 b = *(const float4*)&ffn[base];
  float v0 = a.x + b.x, v1 = a.y + b.y, v2 = a.z + b.z, v3 = a.w + b.w;
  float s1 = v0 + v1 + v2 + v3;
  float s2 = v0 * v0 + v1 * v1 + v2 * v2 + v3 * v3;
#pragma unroll
  for (int off = 32; off; off >>= 1) { s1 += __shfl_down(s1, off); s2 += __shfl_down(s2, off); }
  __shared__ float ra[4], rb[4], rc[4], rd[4];
  if (lane == 0) { ra[wid] = s1; rb[wid] = s2; }
  __syncthreads();
  s1 = ra[0] + ra[1] + ra[2] + ra[3];
  s2 = rb[0] + rb[1] + rb[2] + rb[3];
  float mean = s1 * (1.f / 1024.f);
  float var = s2 * (1.f / 1024.f) - mean * mean;
  float rstd = rsqrtf(var + 1e-5f);
  float4 sv = *(const float4*)&s2c[t * 4];
  float4 bv = *(const float4*)&b2c[t * 4];
  float o0 = (v0 - mean) * rstd * sv.x + bv.x;
  float o1 = (v1 - mean) * rstd * sv.y + bv.y;
  float o2 = (v2 - mean) * rstd * sv.z + bv.z;
  float o3 = (v3 - mean) * rstd * sv.w + bv.w;
  float u1 = o0 + o1 + o2 + o3;
  float u2 = o0 * o0 + o1 * o1 + o2 * o2 + o3 * o3;
#pragma unroll
  for (int off = 32; off; off >>= 1) { u1 += __shfl_down(u1, off); u2 += __shfl_down(u2, off); }
  if (lane == 0) { rc[wid] = u1; rd[wid] = u2; }
  __syncthreads();
  u1 = rc[0] + rc[1] + rc[2] + rc[3];
  u2 = rd[0] + rd[1] + rd[2] + rd[3];
  float mean2 = u1 * (1.f / 1024.f);
  float var2 = u2 * (1.f / 1024.f) - mean2 * mean2;
  float rstd2 = rsqrtf(var2 + 1e-5f);
  float4 s3v = *(const float4*)&s3c[t * 4];
  float4 b3v = *(const float4*)&b3c[t * 4];
  float4 fo;
  fo.x = (o0 - mean2) * rstd2 * s3v.x + b3v.x;
  fo.y = (o1 - mean2) * rstd2 * s3v.y + b3v.y;
  fo.z = (o2 - mean2) * rstd2 * s3v.z + b3v.z;
  fo.w = (o3 - mean2) * rstd2 * s3v.w + b3v.w;
  *(float4*)&out[base] = fo;
}

// ------------------------------------------------------------------ launch
extern "C" void kernel_launch(void* const* d_in, const int* in_sizes, int n_in,
                              void* d_out, int out_size, void* d_ws, size_t ws_size,
                              hipStream_t stream) {
  (void)in_sizes; (void)n_in; (void)out_size; (void)ws_size;
  const float* x   = (const float*)d_in[0];
  const float* msk = (const float*)d_in[1];
  const float* wq  = (const float*)d_in[2];
  const float* wk  = (const float*)d_in[3];
  const float* wv  = (const float*)d_in[4];
  const float* w1  = (const float*)d_in[5];
  const float* b1  = (const float*)d_in[6];
  const float* w2  = (const float*)d_in[7];
  const float* b2  = (const float*)d_in[8];
  const float* l1s = (const float*)d_in[9];
  const float* l1b = (const float*)d_in[10];
  const float* l2s = (const float*)d_in[11];
  const float* l2b = (const float*)d_in[12];
  const float* l3s = (const float*)d_in[13];
  const float* l3b = (const float*)d_in[14];
  float* outp = (float*)d_out;

  char* ws = (char*)d_ws;
  unsigned short* xb   = (unsigned short*)(ws);                       // 8 MB
  unsigned short* wt   = (unsigned short*)(ws + ((size_t)8  << 20));  // 10 MB
  unsigned short* Qb   = (unsigned short*)(ws + ((size_t)18 << 20));  // 8 MB [B,H,T,DH]
  unsigned short* Kb   = (unsigned short*)(ws + ((size_t)26 << 20));  // 8 MB
  _Float16*       Vtg  = (_Float16*)(ws + ((size_t)34 << 20));        // 8 MB k-shuffled V^T
  unsigned short* attn = (unsigned short*)(ws + ((size_t)42 << 20));  // 8 MB bf16 [B,T,D]
  float* h1            = (float*)(ws + ((size_t)50 << 20));           // 16 MB
  unsigned short* h1b  = (unsigned short*)(ws + ((size_t)18 << 20));  // reuse Qb
  unsigned short* gb   = (unsigned short*)(ws + ((size_t)26 << 20));  // reuse Kb
  float* ffn           = (float*)(ws + ((size_t)34 << 20));           // reuse Vtg+attn

  prep_kernel<<<4096 + 1280, 256, 0, stream>>>((const float4*)x, xb,
                                               wq, wk, wv, w1, w2, wt);
  gemm_qkv<<<dim3(24, 32), 256, 0, stream>>>(xb, wt, Qb, Kb, Vtg);
  flash_attn<<<512, 256, 0, stream>>>(Qb, Kb, Vtg, msk, attn);
  ln_res_kernel<<<4096, 256, 0, stream>>>(x, attn, l1s, l1b, h1, h1b);
  gemm_ffn<1><<<dim3(8, 64), 256, 0, stream>>>(h1b, wt + (size_t)3 * 1024 * 1024, gb, nullptr, b1);
  gemm_ffn<2><<<dim3(8, 64), 256, 0, stream>>>(gb, wt + (size_t)4 * 1024 * 1024, nullptr, ffn, b2);
  ln_double_kernel<<<4096, 256, 0, stream>>>(h1, ffn, l2s, l2b, l3s, l3b, outp);
}

// Round 8
// 246.235 us; speedup vs baseline: 1.1773x; 1.0493x over previous
//
#include <hip/hip_runtime.h>
#include <stdint.h>

// B=4, T=1024, D=1024, H=16, DH=64. fp32 in/out, absmax thr 0.1.
// R8 vs R7:
//  - flash: rotating per-j K-prefetch (kf[j] reloaded for kb+1 right after
//    its S-MFMAs consume it) -> latency hidden WITHOUT the st[8][2] array
//    that spilled in R7 (WRITE_SIZE 15MB->8MB expected). launch_bounds(256)
//    (no min-waves) so compiler doesn't cap at 128 VGPR and spill.
//  - exp2f -> __builtin_amdgcn_exp2f (single v_exp_f32; libm exp2f is a
//    multi-inst call without fast-math).

#define B_  4
#define T_  1024
#define D_  1024
#define H_  16
#define DH_ 64

typedef __attribute__((ext_vector_type(8))) short short8;
typedef __attribute__((ext_vector_type(4))) float floatx4;
typedef __attribute__((ext_vector_type(4))) _Float16 half4;

__device__ __forceinline__ unsigned short f2bf(float f) {
  union { float f; uint32_t u; } a; a.f = f;
  uint32_t r = a.u + 0x7FFFu + ((a.u >> 16) & 1u);
  return (unsigned short)(r >> 16);
}
__device__ __forceinline__ float bf2f(unsigned short u) {
  union { uint32_t u; float f; } a; a.u = ((uint32_t)u) << 16;
  return a.f;
}

#define GLD_LDS16(g, l) __builtin_amdgcn_global_load_lds( \
    (const __attribute__((address_space(1))) unsigned int*)(g), \
    (__attribute__((address_space(3))) unsigned int*)(l), 16, 0, 0)

// ---------------------------------------------- prep: cast x + transpose W
__global__ __launch_bounds__(256)
void prep_kernel(const float4* __restrict__ x4, unsigned short* __restrict__ xb,
                 const float* __restrict__ w0, const float* __restrict__ w1,
                 const float* __restrict__ w2, const float* __restrict__ w3,
                 const float* __restrict__ w4, unsigned short* __restrict__ dst_all) {
  const int t = threadIdx.x;
  if (blockIdx.x < 4096) {
    int idx = blockIdx.x * 256 + t;
    float4 v = x4[idx];
    union { uint2 u; unsigned short s[4]; } o;
    o.s[0] = f2bf(v.x); o.s[1] = f2bf(v.y); o.s[2] = f2bf(v.z); o.s[3] = f2bf(v.w);
    *(uint2*)&xb[(size_t)idx * 4] = o.u;
    return;
  }
  const int b = blockIdx.x - 4096;
  const int z = b >> 8, ky = (b >> 4) & 15, nx = b & 15;
  const float* src = (z == 0) ? w0 : (z == 1) ? w1 : (z == 2) ? w2 : (z == 3) ? w3 : w4;
  unsigned short* dst = dst_all + (size_t)z * D_ * D_;
  __shared__ __align__(16) unsigned short tile[64 * 72];
  const int k0 = ky * 64, n0 = nx * 64;
#pragma unroll
  for (int c = 0; c < 4; ++c) {
    int idx = c * 256 + t;
    int r = idx >> 4, cc = (idx & 15) << 2;
    float4 v = *(const float4*)&src[(size_t)(k0 + r) * D_ + n0 + cc];
    tile[(cc + 0) * 72 + r] = f2bf(v.x);
    tile[(cc + 1) * 72 + r] = f2bf(v.y);
    tile[(cc + 2) * 72 + r] = f2bf(v.z);
    tile[(cc + 3) * 72 + r] = f2bf(v.w);
  }
  __syncthreads();
  int rr = t >> 2, ck = (t & 3) << 4;
  uint4 v0 = *(const uint4*)&tile[rr * 72 + ck];
  uint4 v1 = *(const uint4*)&tile[rr * 72 + ck + 8];
  *(uint4*)&dst[(size_t)(n0 + rr) * D_ + k0 + ck] = v0;
  *(uint4*)&dst[(size_t)(n0 + rr) * D_ + k0 + ck + 8] = v1;
}

// ------------------------------------------------------------------ QKV GEMM
// Q pre-scaled by 0.125*log2(e); Q,K bf16 -> [B,H,T,DH]; V fp16 k-shuffled
// V^T [d][kb][quad][j][r] staged via LDS for coalesced stores.
__global__ __launch_bounds__(256, 2)
void gemm_qkv(const unsigned short* __restrict__ A,
              const unsigned short* __restrict__ Bt,
              unsigned short* __restrict__ oQ, unsigned short* __restrict__ oK,
              _Float16* __restrict__ oV) {
  const int K = 1024;
  __shared__ __align__(16) unsigned short As[128 * 32];
  __shared__ __align__(16) unsigned short Bs[128 * 32];
  __shared__ __align__(16) _Float16 Cs[2 * 64 * 136];
  const int t = threadIdx.x;
  const int lane = t & 63, w = t >> 6;
  const int quad = lane >> 4, lm = lane & 15;
  const int wm = w >> 1, wn = w & 1;
  const int m0 = blockIdx.y * 128, n0 = blockIdx.x * 128;
  const int arow = w * 32 + (lane >> 2), acol = (lane & 3) << 3;

  floatx4 acc[4][4];
#pragma unroll
  for (int i = 0; i < 4; ++i)
#pragma unroll
    for (int j = 0; j < 4; ++j) acc[i][j] = (floatx4){0.f, 0.f, 0.f, 0.f};

  for (int kt = 0; kt < K; kt += 32) {
    const unsigned short* ga = A + (size_t)(m0 + arow) * K + kt + acol;
    const unsigned short* gb = Bt + (size_t)(n0 + arow) * K + kt + acol;
    GLD_LDS16(ga, &As[(w * 32) * 32]);
    GLD_LDS16(ga + (size_t)16 * K, &As[(w * 32 + 16) * 32]);
    GLD_LDS16(gb, &Bs[(w * 32) * 32]);
    GLD_LDS16(gb + (size_t)16 * K, &Bs[(w * 32 + 16) * 32]);
    __syncthreads();
    short8 a[4], b[4];
#pragma unroll
    for (int i = 0; i < 4; ++i) a[i] = *(const short8*)&As[(wm * 64 + i * 16 + lm) * 32 + quad * 8];
#pragma unroll
    for (int j = 0; j < 4; ++j) b[j] = *(const short8*)&Bs[(wn * 64 + j * 16 + lm) * 32 + quad * 8];
#pragma unroll
    for (int i = 0; i < 4; ++i)
#pragma unroll
      for (int j = 0; j < 4; ++j)
        acc[i][j] = __builtin_amdgcn_mfma_f32_16x16x32_bf16(a[i], b[j], acc[i][j], 0, 0, 0);
    __syncthreads();
  }

  if (n0 < 2048) {
    unsigned short* p = (n0 < 1024) ? oQ : oK;
    const float qscale = (n0 < 1024) ? 0.18033688f : 1.0f;   // 0.125*log2(e)
#pragma unroll
    for (int i = 0; i < 4; ++i) {
      int gmb = m0 + wm * 64 + i * 16 + quad * 4;
#pragma unroll
      for (int j = 0; j < 4; ++j) {
        int gn = n0 + wn * 64 + j * 16 + lm;
        int nn = gn & 1023, hh = nn >> 6, dd = nn & 63;
#pragma unroll
        for (int r = 0; r < 4; ++r) {
          int gm = gmb + r;
          int bb = gm >> 10, tt = gm & 1023;
          p[(((size_t)bb * H_ + hh) * T_ + tt) * DH_ + dd] = f2bf(acc[i][j][r] * qscale);
        }
      }
    }
  } else {
#pragma unroll
    for (int i = 0; i < 4; ++i) {
#pragma unroll
      for (int j = 0; j < 4; ++j) {
        int gn = n0 + wn * 64 + j * 16 + lm;
        int hd = (gn >> 6) & 1, dd = gn & 63;
        int kperm = quad * 32 + (wm * 4 + i) * 4;
        union { _Float16 h[4]; uint2 u; } pk;
#pragma unroll
        for (int r = 0; r < 4; ++r) pk.h[r] = (_Float16)acc[i][j][r];
        *(uint2*)&Cs[((size_t)(hd * 64 + dd)) * 136 + kperm] = pk.u;
      }
    }
    __syncthreads();
    const int row = t >> 1, half = t & 1;
    const int hd = row >> 6, dd = row & 63;
    const int hh = ((n0 & 1023) >> 6) + hd;
    const int bb = m0 >> 10, kbg = (m0 >> 7) & 7;
    const _Float16* srcp = &Cs[(size_t)(hd * 64 + dd) * 136 + half * 64];
    _Float16* dstp = oV + ((((size_t)bb * H_ + hh) * DH_ + dd) * 8 + kbg) * 128 + half * 64;
#pragma unroll
    for (int g = 0; g < 8; ++g)
      *(uint4*)(dstp + g * 8) = *(const uint4*)(srcp + g * 8);
  }
}

// ------------------------------------------------------------ FFN GEMM 64x128
template <int MODE>
__global__ __launch_bounds__(256, 2)
void gemm_ffn(const unsigned short* __restrict__ A,
              const unsigned short* __restrict__ Bt,
              unsigned short* __restrict__ oBf, float* __restrict__ oF,
              const float* __restrict__ bias) {
  const int K = 1024, N = 1024;
  __shared__ __align__(16) unsigned short As[64 * 32];
  __shared__ __align__(16) unsigned short Bs[128 * 32];
  const int t = threadIdx.x;
  const int lane = t & 63, w = t >> 6;
  const int quad = lane >> 4, lm = lane & 15;
  const int wm = w >> 1, wn = w & 1;
  const int m0 = blockIdx.y * 64, n0 = blockIdx.x * 128;
  const int lrow = lane >> 2, lcol = (lane & 3) << 3;

  floatx4 acc[2][4];
#pragma unroll
  for (int i = 0; i < 2; ++i)
#pragma unroll
    for (int j = 0; j < 4; ++j) acc[i][j] = (floatx4){0.f, 0.f, 0.f, 0.f};

  for (int kt = 0; kt < K; kt += 32) {
    const unsigned short* ga = A + (size_t)(m0 + w * 16 + lrow) * K + kt + lcol;
    const unsigned short* gb = Bt + (size_t)(n0 + w * 32 + lrow) * K + kt + lcol;
    GLD_LDS16(ga, &As[(w * 16) * 32]);
    GLD_LDS16(gb, &Bs[(w * 32) * 32]);
    GLD_LDS16(gb + (size_t)16 * K, &Bs[(w * 32 + 16) * 32]);
    __syncthreads();
    short8 a[2], b[4];
#pragma unroll
    for (int i = 0; i < 2; ++i) a[i] = *(const short8*)&As[(wm * 32 + i * 16 + lm) * 32 + quad * 8];
#pragma unroll
    for (int j = 0; j < 4; ++j) b[j] = *(const short8*)&Bs[(wn * 64 + j * 16 + lm) * 32 + quad * 8];
#pragma unroll
    for (int i = 0; i < 2; ++i)
#pragma unroll
      for (int j = 0; j < 4; ++j)
        acc[i][j] = __builtin_amdgcn_mfma_f32_16x16x32_bf16(a[i], b[j], acc[i][j], 0, 0, 0);
    __syncthreads();
  }

#pragma unroll
  for (int i = 0; i < 2; ++i) {
    int gmb = m0 + wm * 32 + i * 16 + quad * 4;
#pragma unroll
    for (int j = 0; j < 4; ++j) {
      int gn = n0 + wn * 64 + j * 16 + lm;
      float bv = bias[gn];
#pragma unroll
      for (int r = 0; r < 4; ++r) {
        int gm = gmb + r;
        float v = acc[i][j][r] + bv;
        if (MODE == 1) {
          oBf[(size_t)gm * N + gn] = f2bf(fmaxf(v, 0.f));
        } else {
          oF[(size_t)gm * N + gn] = v;
        }
      }
    }
  }
}

// --------------------------------------------------------------- flash attn
// 512 blocks x 256 thr; waves independent; no LDS. Rotating per-j K-prefetch:
// inside the j-loop, right after kf[j]'s S-MFMAs issue, kb+1's K fragment is
// loaded into kf[j] (WAR handled by regalloc; ~7 j-steps to land). No bulk
// st array -> no spill. Q pre-scaled so st is log2-domain already.
// Wave 3 of qb==7 blocks loops kb=0..7 with row 1023 never masked.
__global__ __launch_bounds__(256)
void flash_attn(const unsigned short* __restrict__ Qb,
                const unsigned short* __restrict__ Kb,
                const _Float16* __restrict__ Vtg,
                const float* __restrict__ maskp,
                unsigned short* __restrict__ attn) {
  const int t = threadIdx.x;
  const int lane = t & 63, w = t >> 6;
  const int quad = lane >> 4, lm = lane & 15;

  const int bid = blockIdx.x;
  const int hi = bid >> 8, lo = bid & 255;
  const int qraw = lo & 7;
  const int qb = hi ? (7 - qraw) : qraw;
  const int hb = (lo >> 3) | (hi << 5);
  const int hh = hb & 15, bb = hb >> 4;
  const int q0 = qb << 7;

  const size_t headoff = ((size_t)bb * H_ + hh) * T_ * DH_;
  const unsigned short* Qh = Qb + headoff;
  const unsigned short* Kh = Kb + headoff;
  const _Float16* Vh = Vtg + headoff;   // k-shuffled [d][kb][quad][j][r]

  short8 qf[2][2];
#pragma unroll
  for (int qg = 0; qg < 2; ++qg)
#pragma unroll
    for (int ks = 0; ks < 2; ++ks)
      qf[qg][ks] = *(const short8*)(Qh + (size_t)(q0 + w * 32 + qg * 16 + lm) * 64 + ks * 32 + quad * 8);

  float lsum[2] = {0.f, 0.f};
  floatx4 acc[2][4];
#pragma unroll
  for (int qg = 0; qg < 2; ++qg)
#pragma unroll
    for (int j2 = 0; j2 < 4; ++j2) acc[qg][j2] = (floatx4){0.f, 0.f, 0.f, 0.f};

  const int qglob0 = q0 + w * 32 + lm;
  const bool excl1 = (qglob0 + 16 == 1023);   // row-1023 lane (qg=1 only)
  const float MSHIFT = 14426.950408f;          // 10000*log2(e)

  const int kb_lo = (qb == 7 && w == 3) ? 0 : qb;

  // prologue: K fragments for kb_lo
  short8 kf[8][2];
  {
    const unsigned short* Kblk = Kh + (size_t)(kb_lo * 128) * 64;
#pragma unroll
    for (int j = 0; j < 8; ++j) {
      kf[j][0] = *(const short8*)(Kblk + (size_t)(j * 16 + lm) * 64 + quad * 8);
      kf[j][1] = *(const short8*)(Kblk + (size_t)(j * 16 + lm) * 64 + 32 + quad * 8);
    }
  }

  for (int kb = kb_lo; kb < 8; ++kb) {
    const int k0 = kb * 128;
    const bool need_mask = (kb <= qb);
    const bool has_next = (kb + 1 < 8);
    const unsigned short* Kn = Kh + (size_t)((kb + 1) * 128) * 64;

    // V loads for this kb (consumed in PV; hidden by S+softmax of j=0..)
    union { uint4 u[4]; _Float16 h[32]; } vf[4];
#pragma unroll
    for (int j2 = 0; j2 < 4; ++j2) {
      const _Float16* vp = Vh + ((size_t)(j2 * 16 + lm) * 8 + kb) * 128 + quad * 32;
#pragma unroll
      for (int g = 0; g < 4; ++g) vf[j2].u[g] = *(const uint4*)(vp + g * 8);
    }

#pragma unroll
    for (int j = 0; j < 8; ++j) {
      // S-MFMAs consume kf[j]
      floatx4 st[2];
#pragma unroll
      for (int qg = 0; qg < 2; ++qg) {
        floatx4 z = (floatx4){0.f, 0.f, 0.f, 0.f};
        z = __builtin_amdgcn_mfma_f32_16x16x32_bf16(kf[j][0], qf[qg][0], z, 0, 0, 0);
        st[qg] = __builtin_amdgcn_mfma_f32_16x16x32_bf16(kf[j][1], qf[qg][1], z, 0, 0, 0);
      }
      // rotate: prefetch kb+1's fragment j into kf[j] (lands ~7 j-steps later)
      if (has_next) {
        kf[j][0] = *(const short8*)(Kn + (size_t)(j * 16 + lm) * 64 + quad * 8);
        kf[j][1] = *(const short8*)(Kn + (size_t)(j * 16 + lm) * 64 + 32 + quad * 8);
      }
      // softmax j
      half4 pa[2];
#pragma unroll
      for (int qg = 0; qg < 2; ++qg) {
        const int qq = qglob0 + qg * 16;
        const bool skip = (qg == 1) && excl1;
#pragma unroll
        for (int r = 0; r < 4; ++r) {
          int kg = k0 + j * 16 + quad * 4 + r;
          float v = st[qg][r];
          if (need_mask && !skip && kg <= qq) v -= MSHIFT;
          float p = __builtin_amdgcn_exp2f(v);
          lsum[qg] += p;
          pa[qg][r] = (_Float16)p;
        }
      }
      // PV j
#pragma unroll
      for (int j2 = 0; j2 < 4; ++j2) {
        half4 vb;
#pragma unroll
        for (int r = 0; r < 4; ++r) vb[r] = vf[j2].h[j * 4 + r];
        acc[0][j2] = __builtin_amdgcn_mfma_f32_16x16x16f16(pa[0], vb, acc[0][j2], 0, 0, 0);
        acc[1][j2] = __builtin_amdgcn_mfma_f32_16x16x16f16(pa[1], vb, acc[1][j2], 0, 0, 0);
      }
    }
  }

  // epilogue
#pragma unroll
  for (int qg = 0; qg < 2; ++qg) {
    float l = lsum[qg];
    l += __shfl_xor(l, 16);
    l += __shfl_xor(l, 32);
    float s = maskp[bb * T_ + qglob0 + qg * 16] / l;
#pragma unroll
    for (int r = 0; r < 4; ++r) {
      float bsc = __shfl(s, quad * 4 + r);
      int tq = q0 + w * 32 + qg * 16 + quad * 4 + r;
#pragma unroll
      for (int j2 = 0; j2 < 4; ++j2)
        attn[((size_t)(bb * T_ + tq)) * D_ + hh * 64 + j2 * 16 + lm] = f2bf(acc[qg][j2][r] * bsc);
    }
  }
}

// --------------------------------------------- LN(x + attn_bf16) -> h1 f32+bf16
__global__ __launch_bounds__(256)
void ln_res_kernel(const float* __restrict__ xa, const unsigned short* __restrict__ attn,
                   const float* __restrict__ sc, const float* __restrict__ bi,
                   float* __restrict__ h, unsigned short* __restrict__ hb) {
  const int row = blockIdx.x, t = threadIdx.x;
  const int lane = t & 63, wid = t >> 6;
  size_t base = (size_t)row * D_ + t * 4;
  float4 a = *(const float4*)&xa[base];
  union { uint2 u; unsigned short s[4]; } au;
  au.u = *(const uint2*)&attn[base];
  float v0 = a.x + bf2f(au.s[0]), v1 = a.y + bf2f(au.s[1]);
  float v2 = a.z + bf2f(au.s[2]), v3 = a.w + bf2f(au.s[3]);
  float s1 = v0 + v1 + v2 + v3;
  float s2 = v0 * v0 + v1 * v1 + v2 * v2 + v3 * v3;
#pragma unroll
  for (int off = 32; off; off >>= 1) { s1 += __shfl_down(s1, off); s2 += __shfl_down(s2, off); }
  __shared__ float r1[4], r2[4];
  if (lane == 0) { r1[wid] = s1; r2[wid] = s2; }
  __syncthreads();
  s1 = r1[0] + r1[1] + r1[2] + r1[3];
  s2 = r2[0] + r2[1] + r2[2] + r2[3];
  float mean = s1 * (1.f / 1024.f);
  float var = s2 * (1.f / 1024.f) - mean * mean;
  float rstd = rsqrtf(var + 1e-5f);
  float4 sv = *(const float4*)&sc[t * 4];
  float4 bv = *(const float4*)&bi[t * 4];
  float o0 = (v0 - mean) * rstd * sv.x + bv.x;
  float o1 = (v1 - mean) * rstd * sv.y + bv.y;
  float o2 = (v2 - mean) * rstd * sv.z + bv.z;
  float o3 = (v3 - mean) * rstd * sv.w + bv.w;
  float4 ov = {o0, o1, o2, o3};
  *(float4*)&h[base] = ov;
  union { uint2 u; unsigned short s[4]; } ob;
  ob.s[0] = f2bf(o0); ob.s[1] = f2bf(o1); ob.s[2] = f2bf(o2); ob.s[3] = f2bf(o3);
  *(uint2*)&hb[base] = ob.u;
}

// --------------------------------------- out = LN(LN(h1+ffn,ln2),ln3)
__global__ __launch_bounds__(256)
void ln_double_kernel(const float* __restrict__ h1, const float* __restrict__ ffn,
                      const float* __restrict__ s2c, const float* __restrict__ b2c,
                      const float* __restrict__ s3c, const float* __restrict__ b3c,
                      float* __restrict__ out) {
  const int row = blockIdx.x, t = threadIdx.x;
  const int lane = t & 63, wid = t >> 6;
  size_t base = (size_t)row * D_ + t * 4;
  float4 a = *(const float4*)&h1[base];
  float4 b = *(const float4*)&ffn[base];
  float v0 = a.x + b.x, v1 = a.y + b.y, v2 = a.z + b.z, v3 = a.w + b.w;
  float s1 = v0 + v1 + v2 + v3;
  float s2 = v0 * v0 + v1 * v1 + v2 * v2 + v3 * v3;
#pragma unroll
  for (int off = 32; off; off >>= 1) { s1 += __shfl_down(s1, off); s2 += __shfl_down(s2, off); }
  __shared__ float ra[4], rb[4], rc[4], rd[4];
  if (lane == 0) { ra[wid] = s1; rb[wid] = s2; }
  __syncthreads();
  s1 = ra[0] + ra[1] + ra[2] + ra[3];
  s2 = rb[0] + rb[1] + rb[2] + rb[3];
  float mean = s1 * (1.f / 1024.f);
  float var = s2 * (1.f / 1024.f) - mean * mean;
  float rstd = rsqrtf(var + 1e-5f);
  float4 sv = *(const float4*)&s2c[t * 4];
  float4 bv = *(const float4*)&b2c[t * 4];
  float o0 = (v0 - mean) * rstd * sv.x + bv.x;
  float o1 = (v1 - mean) * rstd * sv.y + bv.y;
  float o2 = (v2 - mean) * rstd * sv.z + bv.z;
  float o3 = (v3 - mean) * rstd * sv.w + bv.w;
  float u1 = o0 + o1 + o2 + o3;
  float u2 = o0 * o0 + o1 * o1 + o2 * o2 + o3 * o3;
#pragma unroll
  for (int off = 32; off; off >>= 1) { u1 += __shfl_down(u1, off); u2 += __shfl_down(u2, off); }
  if (lane == 0) { rc[wid] = u1; rd[wid] = u2; }
  __syncthreads();
  u1 = rc[0] + rc[1] + rc[2] + rc[3];
  u2 = rd[0] + rd[1] + rd[2] + rd[3];
  float mean2 = u1 * (1.f / 1024.f);
  float var2 = u2 * (1.f / 1024.f) - mean2 * mean2;
  float rstd2 = rsqrtf(var2 + 1e-5f);
  float4 s3v = *(const float4*)&s3c[t * 4];
  float4 b3v = *(const float4*)&b3c[t * 4];
  float4 fo;
  fo.x = (o0 - mean2) * rstd2 * s3v.x + b3v.x;
  fo.y = (o1 - mean2) * rstd2 * s3v.y + b3v.y;
  fo.z = (o2 - mean2) * rstd2 * s3v.z + b3v.z;
  fo.w = (o3 - mean2) * rstd2 * s3v.w + b3v.w;
  *(float4*)&out[base] = fo;
}

// ------------------------------------------------------------------ launch
extern "C" void kernel_launch(void* const* d_in, const int* in_sizes, int n_in,
                              void* d_out, int out_size, void* d_ws, size_t ws_size,
                              hipStream_t stream) {
  (void)in_sizes; (void)n_in; (void)out_size; (void)ws_size;
  const float* x   = (const float*)d_in[0];
  const float* msk = (const float*)d_in[1];
  const float* wq  = (const float*)d_in[2];
  const float* wk  = (const float*)d_in[3];
  const float* wv  = (const float*)d_in[4];
  const float* w1  = (const float*)d_in[5];
  const float* b1  = (const float*)d_in[6];
  const float* w2  = (const float*)d_in[7];
  const float* b2  = (const float*)d_in[8];
  const float* l1s = (const float*)d_in[9];
  const float* l1b = (const float*)d_in[10];
  const float* l2s = (const float*)d_in[11];
  const float* l2b = (const float*)d_in[12];
  const float* l3s = (const float*)d_in[13];
  const float* l3b = (const float*)d_in[14];
  float* outp = (float*)d_out;

  char* ws = (char*)d_ws;
  unsigned short* xb   = (unsigned short*)(ws);                       // 8 MB
  unsigned short* wt   = (unsigned short*)(ws + ((size_t)8  << 20));  // 10 MB
  unsigned short* Qb   = (unsigned short*)(ws + ((size_t)18 << 20));  // 8 MB [B,H,T,DH]
  unsigned short* Kb   = (unsigned short*)(ws + ((size_t)26 << 20));  // 8 MB
  _Float16*       Vtg  = (_Float16*)(ws + ((size_t)34 << 20));        // 8 MB k-shuffled V^T
  unsigned short* attn = (unsigned short*)(ws + ((size_t)42 << 20));  // 8 MB bf16 [B,T,D]
  float* h1            = (float*)(ws + ((size_t)50 << 20));           // 16 MB
  unsigned short* h1b  = (unsigned short*)(ws + ((size_t)18 << 20));  // reuse Qb
  unsigned short* gb   = (unsigned short*)(ws + ((size_t)26 << 20));  // reuse Kb
  float* ffn           = (float*)(ws + ((size_t)34 << 20));           // reuse Vtg+attn

  prep_kernel<<<4096 + 1280, 256, 0, stream>>>((const float4*)x, xb,
                                               wq, wk, wv, w1, w2, wt);
  gemm_qkv<<<dim3(24, 32), 256, 0, stream>>>(xb, wt, Qb, Kb, Vtg);
  flash_attn<<<512, 256, 0, stream>>>(Qb, Kb, Vtg, msk, attn);
  ln_res_kernel<<<4096, 256, 0, stream>>>(x, attn, l1s, l1b, h1, h1b);
  gemm_ffn<1><<<dim3(8, 64), 256, 0, stream>>>(h1b, wt + (size_t)3 * 1024 * 1024, gb, nullptr, b1);
  gemm_ffn<2><<<dim3(8, 64), 256, 0, stream>>>(gb, wt + (size_t)4 * 1024 * 1024, nullptr, ffn, b2);
  ln_double_kernel<<<4096, 256, 0, stream>>>(h1, ffn, l2s, l2b, l3s, l3b, outp);
}